// Round 1
// baseline (1115.910 us; speedup 1.0000x reference)
//
#include <hip/hip_runtime.h>
#include <math.h>

#define BB 4
#define NN 2048
#define DD 512
#define EE 8
#define HH 1365
#define H2 2730
#define CAP 320
#define NT (BB*NN)   // 8192

// ---------------- helpers ----------------
__device__ __forceinline__ float gelu_exact(float x){
    return 0.5f * x * (1.0f + erff(x * 0.70710678118654752f));
}
__device__ __forceinline__ unsigned rotl32(unsigned x, int d){ return (x<<d)|(x>>(32-d)); }
__device__ __forceinline__ void tf_round(unsigned &x0, unsigned &x1, int r){
    x0 += x1; x1 = rotl32(x1, r); x1 ^= x0;
}
// jax.random.uniform(key(42), (2,4,2048))[1].ravel()[t]
__device__ float threefry_u01_second(unsigned t){
    const unsigned ks0 = 0u, ks1 = 42u, ks2 = 0x1BD11BDAu ^ 42u;
    unsigned x0 = t, x1 = t + 8192u;
    x0 += ks0; x1 += ks1;
    tf_round(x0,x1,13); tf_round(x0,x1,15); tf_round(x0,x1,26); tf_round(x0,x1,6);
    x0 += ks1; x1 += ks2 + 1u;
    tf_round(x0,x1,17); tf_round(x0,x1,29); tf_round(x0,x1,16); tf_round(x0,x1,24);
    x0 += ks2; x1 += ks0 + 2u;
    tf_round(x0,x1,13); tf_round(x0,x1,15); tf_round(x0,x1,26); tf_round(x0,x1,6);
    x0 += ks0; x1 += ks1 + 3u;
    tf_round(x0,x1,17); tf_round(x0,x1,29); tf_round(x0,x1,16); tf_round(x0,x1,24);
    x0 += ks1; x1 += ks2 + 4u;
    tf_round(x0,x1,13); tf_round(x0,x1,15); tf_round(x0,x1,26); tf_round(x0,x1,6);
    x0 += ks2; x1 += ks0 + 5u;
    unsigned bits = (x1 >> 9) | 0x3f800000u;
    return __uint_as_float(bits) - 1.0f;
}

// ---------------- kernels ----------------
__global__ void k_init(int* slot_tok, int* tok_c0, int* tok_c1, float* dp, float* z2){
    int i = blockIdx.x*256 + threadIdx.x;
    if (i < BB*EE*CAP) slot_tok[i] = -1;
    if (i < NT){ tok_c0[i] = -1; tok_c1[i] = -1; }
    if (i < BB*EE) dp[i] = 0.f;
    if (i == 0) z2[0] = 0.f;
}

__global__ void k_rmsnorm(const float* __restrict__ x, const float* __restrict__ g,
                          float* __restrict__ xg){
    int t = blockIdx.x;
    const float* row = x + (size_t)t * DD;
    float v[2]; float s = 0.f;
    #pragma unroll
    for (int i=0;i<2;i++){ v[i] = row[threadIdx.x + i*256]; s += v[i]*v[i]; }
    __shared__ float red[4];
    #pragma unroll
    for (int off=32; off; off>>=1) s += __shfl_down(s, off);
    if ((threadIdx.x & 63)==0) red[threadIdx.x>>6] = s;
    __syncthreads();
    float ss = red[0]+red[1]+red[2]+red[3];
    float nrm = fmaxf(sqrtf(ss), 1e-12f);
    float scale = 22.62741699796952f / nrm;   // sqrt(512)
    #pragma unroll
    for (int i=0;i<2;i++){
        int d = threadIdx.x + i*256;
        xg[(size_t)t*DD + d] = v[i] * scale * g[d];
    }
}

__global__ void k_gate(const float* __restrict__ xg, const float* __restrict__ gw,
                       int* tok_e0, int* tok_e1, float* tok_g0, float* tok_g1,
                       float* dp, float* z2){
    int wave = threadIdx.x >> 6;
    int lane = threadIdx.x & 63;
    int t = blockIdx.x*4 + wave;
    int b = t / NN;
    float acc[EE];
    #pragma unroll
    for (int e=0;e<EE;e++) acc[e]=0.f;
    const float* row = xg + (size_t)t*DD;
    for (int i=0;i<8;i++){
        int k = lane + i*64;
        float xv = row[k];
        const float* w = gw + k*EE;
        #pragma unroll
        for (int e=0;e<EE;e++) acc[e] = fmaf(xv, w[e], acc[e]);
    }
    #pragma unroll
    for (int off=32; off; off>>=1){
        #pragma unroll
        for (int e=0;e<EE;e++) acc[e] += __shfl_down(acc[e], off);
    }
    __shared__ float s_raw[4][EE];
    __shared__ float s_z2[4];
    if (lane==0){
        float mx = acc[0];
        #pragma unroll
        for (int e=1;e<EE;e++) mx = fmaxf(mx, acc[e]);
        float p[EE]; float se=0.f;
        #pragma unroll
        for (int e=0;e<EE;e++){ p[e] = expf(acc[e]-mx); se += p[e]; }
        float inv = 1.f/se;
        #pragma unroll
        for (int e=0;e<EE;e++) p[e] *= inv;
        float z = mx + logf(se);
        int i0=0;
        #pragma unroll
        for (int e=1;e<EE;e++) if (p[e] > p[i0]) i0=e;
        int i1 = (i0==0)?1:0;
        #pragma unroll
        for (int e=0;e<EE;e++){ if (e==i0) continue; if (p[e] > p[i1]) i1=e; }
        float g0=p[i0], g1=p[i1];
        float denom = fmaxf(g0+g1, 1e-9f);
        g0/=denom; g1/=denom;
        float prob = threefry_u01_second((unsigned)t);
        bool route1 = prob < (g1 * 5.0f);       // g1 / 0.2
        tok_e0[t] = i0;
        tok_e1[t] = route1 ? i1 : -1;
        tok_g0[t] = g0;
        tok_g1[t] = g1;
        #pragma unroll
        for (int e=0;e<EE;e++) s_raw[wave][e] = p[e];
        s_z2[wave] = z*z;
    }
    __syncthreads();
    if (threadIdx.x < EE){
        float sum = s_raw[0][threadIdx.x]+s_raw[1][threadIdx.x]+s_raw[2][threadIdx.x]+s_raw[3][threadIdx.x];
        atomicAdd(&dp[b*EE + threadIdx.x], sum);
    }
    if (threadIdx.x == EE) atomicAdd(z2, s_z2[0]+s_z2[1]+s_z2[2]+s_z2[3]);
}

__global__ void k_scan(const int* __restrict__ tok_e0, const int* __restrict__ tok_e1,
                       int* tok_c0, int* tok_c1, int* slot_tok, int* kept0cnt){
    int be = blockIdx.x;
    int b = be >> 3, e = be & 7;
    int tid = threadIdx.x;      // 256 threads, 8 tokens each
    int n0 = tid * 8;
    int base_t = b*NN;
    int m0=0, m1=0;
    for (int i=0;i<8;i++){
        int t = base_t + n0 + i;
        m0 += (tok_e0[t]==e);
        m1 += (tok_e1[t]==e);
    }
    __shared__ int s[256];
    s[tid] = m0 | (m1<<16);
    __syncthreads();
    for (int off=1; off<256; off<<=1){
        int v = 0;
        if (tid >= off) v = s[tid-off];
        __syncthreads();
        if (tid >= off) s[tid] += v;
        __syncthreads();
    }
    int incl = s[tid];
    int total = s[255];
    int p0 = (incl & 0xffff) - m0;
    int p1 = (incl >> 16) - m1;
    int t0 = total & 0xffff;
    int kept0 = min(t0, CAP);
    int c0 = p0, c1 = p1;
    for (int i=0;i<8;i++){
        int n = n0 + i;
        int t = base_t + n;
        if (tok_e0[t]==e){
            int pos = c0++;
            if (pos < CAP){ tok_c0[t] = pos; slot_tok[be*CAP + pos] = n; }
        }
        if (tok_e1[t]==e){
            int pos = kept0 + c1++;
            if (pos < CAP){ tok_c1[t] = pos; slot_tok[be*CAP + pos] = n; }
        }
    }
    if (tid==0) kept0cnt[be] = kept0;
}

__global__ void k_aux(const float* dp, const float* z2, const int* kept0cnt, float* out_aux){
    if (threadIdx.x==0 && blockIdx.x==0){
        float bal = 0.f;
        for (int i=0;i<BB*EE;i++){
            float dpm = dp[i] / (float)NN;
            float d1  = (float)kept0cnt[i] / (float)NN;
            bal += dpm * d1;
        }
        bal = bal / (float)(BB*EE) * (float)(EE*EE);
        float zl = z2[0] / (float)(BB*NN);
        out_aux[0] = 0.01f * bal + 0.001f * zl;
    }
}

// act[be][m][h] = u*gelu(g)*mult_bias  -- tile 64x64, 4x4 per thread
__global__ __launch_bounds__(256) void k_ffn1(const float* __restrict__ xg,
        const float* __restrict__ w1, const float* __restrict__ b1,
        const float* __restrict__ mb, const int* __restrict__ slot_tok,
        float* __restrict__ act){
    int be = blockIdx.z; int b = be>>3, e = be&7;
    int m_base = blockIdx.y * 64;
    int h_base = blockIdx.x * 64;
    const float* W = w1 + (size_t)e * DD * H2;
    __shared__ float As[16][66];
    __shared__ float Bu[16][64];
    __shared__ float Bg[16][64];
    int tid = threadIdx.x;
    int am = tid >> 2;
    int ak4 = (tid & 3) * 4;
    int tok = slot_tok[be*CAP + m_base + am];
    const float* arow = (tok >= 0) ? (xg + ((size_t)(b*NN + tok)) * DD) : nullptr;
    int bk = tid >> 4;
    int bn4 = (tid & 15) * 4;
    int ty = tid >> 4;
    int tx = tid & 15;
    float accu[4][4], accg[4][4];
    #pragma unroll
    for (int i=0;i<4;i++)
        #pragma unroll
        for (int j=0;j<4;j++){ accu[i][j]=0.f; accg[i][j]=0.f; }

    for (int kc = 0; kc < DD; kc += 16){
        if (arow){
            float4 a4 = *(const float4*)(arow + kc + ak4);
            As[ak4+0][am]=a4.x; As[ak4+1][am]=a4.y; As[ak4+2][am]=a4.z; As[ak4+3][am]=a4.w;
        } else {
            As[ak4+0][am]=0.f; As[ak4+1][am]=0.f; As[ak4+2][am]=0.f; As[ak4+3][am]=0.f;
        }
        {
            int kg = kc + bk;
            const float* wrow = W + (size_t)kg * H2;
            #pragma unroll
            for (int j=0;j<4;j++){
                int h = h_base + bn4 + j;
                float u = (h < HH) ? wrow[h]      : 0.f;
                float g = (h < HH) ? wrow[HH + h] : 0.f;
                Bu[bk][bn4+j]=u; Bg[bk][bn4+j]=g;
            }
        }
        __syncthreads();
        #pragma unroll
        for (int kk=0; kk<16; kk++){
            float a[4], u[4], g[4];
            #pragma unroll
            for (int i=0;i<4;i++) a[i] = As[kk][ty + 16*i];
            #pragma unroll
            for (int j=0;j<4;j++){ u[j]=Bu[kk][tx+16*j]; g[j]=Bg[kk][tx+16*j]; }
            #pragma unroll
            for (int i=0;i<4;i++)
                #pragma unroll
                for (int j=0;j<4;j++){
                    accu[i][j] = fmaf(a[i], u[j], accu[i][j]);
                    accg[i][j] = fmaf(a[i], g[j], accg[i][j]);
                }
        }
        __syncthreads();
    }
    #pragma unroll
    for (int j=0;j<4;j++){
        int h = h_base + tx + 16*j;
        if (h >= HH) continue;
        float bu = b1[e*H2 + h], bg = b1[e*H2 + HH + h], mbv = mb[e*HH + h];
        #pragma unroll
        for (int i=0;i<4;i++){
            int m = m_base + ty + 16*i;
            float uv = accu[i][j] + bu;
            float gv = accg[i][j] + bg;
            act[((size_t)be*CAP + m) * HH + h] = uv * gelu_exact(gv) * mbv;
        }
    }
}

// eo[be][m][d] = act @ w2 + b2
__global__ __launch_bounds__(256) void k_ffn2(const float* __restrict__ act,
        const float* __restrict__ w2, const float* __restrict__ b2,
        float* __restrict__ eo){
    int be = blockIdx.z; int e = be&7;
    int m_base = blockIdx.y * 64;
    int n_base = blockIdx.x * 64;
    const float* W = w2 + (size_t)e * HH * DD;
    __shared__ float As[16][66];
    __shared__ float Bs[16][64];
    int tid = threadIdx.x;
    int am = tid >> 2;
    int ak4 = (tid & 3) * 4;
    int bk = tid >> 4;
    int bn4 = (tid & 15) * 4;
    int ty = tid >> 4;
    int tx = tid & 15;
    float acc[4][4];
    #pragma unroll
    for (int i=0;i<4;i++)
        #pragma unroll
        for (int j=0;j<4;j++) acc[i][j]=0.f;
    const float* arow = act + ((size_t)be*CAP + m_base + am)*HH;

    for (int kc=0; kc<HH; kc+=16){
        #pragma unroll
        for (int j=0;j<4;j++){
            int k = kc + ak4 + j;
            As[ak4+j][am] = (k < HH) ? arow[k] : 0.f;
        }
        {
            int kg = kc + bk;
            if (kg < HH){
                float4 b4 = *(const float4*)(W + (size_t)kg*DD + n_base + bn4);
                Bs[bk][bn4+0]=b4.x; Bs[bk][bn4+1]=b4.y; Bs[bk][bn4+2]=b4.z; Bs[bk][bn4+3]=b4.w;
            } else {
                Bs[bk][bn4+0]=0.f; Bs[bk][bn4+1]=0.f; Bs[bk][bn4+2]=0.f; Bs[bk][bn4+3]=0.f;
            }
        }
        __syncthreads();
        #pragma unroll
        for (int kk=0; kk<16; kk++){
            float a[4], bvec[4];
            #pragma unroll
            for (int i=0;i<4;i++) a[i] = As[kk][ty + 16*i];
            #pragma unroll
            for (int j=0;j<4;j++) bvec[j]=Bs[kk][tx+16*j];
            #pragma unroll
            for (int i=0;i<4;i++)
                #pragma unroll
                for (int j=0;j<4;j++)
                    acc[i][j] = fmaf(a[i], bvec[j], acc[i][j]);
        }
        __syncthreads();
    }
    #pragma unroll
    for (int j=0;j<4;j++){
        int d = n_base + tx + 16*j;
        float bb = b2[e*DD + d];
        #pragma unroll
        for (int i=0;i<4;i++){
            int m = m_base + ty + 16*i;
            eo[((size_t)be*CAP + m)*DD + d] = acc[i][j] + bb;
        }
    }
}

__global__ void k_combine(const float* __restrict__ x, const float* __restrict__ eo,
        const int* __restrict__ tok_e0, const int* __restrict__ tok_e1,
        const int* __restrict__ tok_c0, const int* __restrict__ tok_c1,
        const float* __restrict__ tok_g0, const float* __restrict__ tok_g1,
        const float* __restrict__ ln_g, const float* __restrict__ ln_b,
        float* __restrict__ out){
    int t = blockIdx.x;
    int b = t / NN;
    int e0 = tok_e0[t], c0 = tok_c0[t];
    int e1 = tok_e1[t], c1 = tok_c1[t];
    float g0 = tok_g0[t], g1 = tok_g1[t];
    const float* r0 = (c0>=0) ? eo + (((size_t)(b*EE+e0))*CAP + c0)*DD : nullptr;
    const float* r1 = (e1>=0 && c1>=0) ? eo + (((size_t)(b*EE+e1))*CAP + c1)*DD : nullptr;
    float y[2]; float s=0.f, s2=0.f;
    #pragma unroll
    for (int i=0;i<2;i++){
        int d = threadIdx.x + i*256;
        float v = x[(size_t)t*DD + d];
        if (r0) v = fmaf(g0, r0[d], v);
        if (r1) v = fmaf(g1, r1[d], v);
        y[i]=v; s+=v; s2+=v*v;
    }
    __shared__ float rs[4], rs2[4];
    #pragma unroll
    for (int off=32; off; off>>=1){ s+=__shfl_down(s,off); s2+=__shfl_down(s2,off); }
    if ((threadIdx.x&63)==0){ rs[threadIdx.x>>6]=s; rs2[threadIdx.x>>6]=s2; }
    __syncthreads();
    float mu  = (rs[0]+rs[1]+rs[2]+rs[3]) * (1.0f/512.0f);
    float var = (rs2[0]+rs2[1]+rs2[2]+rs2[3]) * (1.0f/512.0f) - mu*mu;
    float inv = rsqrtf(var + 1e-5f);
    #pragma unroll
    for (int i=0;i<2;i++){
        int d = threadIdx.x + i*256;
        out[(size_t)t*DD + d] = (y[i]-mu)*inv*ln_g[d] + ln_b[d];
    }
}

extern "C" void kernel_launch(void* const* d_in, const int* in_sizes, int n_in,
                              void* d_out, int out_size, void* d_ws, size_t ws_size,
                              hipStream_t stream) {
    const float* x         = (const float*)d_in[0];
    const float* gate_w    = (const float*)d_in[1];
    const float* prenorm_g = (const float*)d_in[2];
    const float* w1        = (const float*)d_in[3];
    const float* b1        = (const float*)d_in[4];
    const float* mult_bias = (const float*)d_in[5];
    const float* w2        = (const float*)d_in[6];
    const float* b2        = (const float*)d_in[7];
    const float* ln_g      = (const float*)d_in[8];
    const float* ln_b      = (const float*)d_in[9];
    float* out = (float*)d_out;

    char* p = (char*)d_ws;
    float* xg  = (float*)p; p += (size_t)NT*DD*4;
    float* act = (float*)p; p += (size_t)BB*EE*CAP*HH*4;
    float* eo  = (float*)p; p += (size_t)BB*EE*CAP*DD*4;
    int* slot_tok = (int*)p; p += BB*EE*CAP*4;
    int* tok_e0 = (int*)p; p += NT*4;
    int* tok_e1 = (int*)p; p += NT*4;
    int* tok_c0 = (int*)p; p += NT*4;
    int* tok_c1 = (int*)p; p += NT*4;
    float* tok_g0 = (float*)p; p += NT*4;
    float* tok_g1 = (float*)p; p += NT*4;
    float* dp = (float*)p; p += BB*EE*4;
    float* z2 = (float*)p; p += 4;
    int* kept0 = (int*)p; p += BB*EE*4;

    k_init<<<40, 256, 0, stream>>>(slot_tok, tok_c0, tok_c1, dp, z2);
    k_rmsnorm<<<NT, 256, 0, stream>>>(x, prenorm_g, xg);
    k_gate<<<NT/4, 256, 0, stream>>>(xg, gate_w, tok_e0, tok_e1, tok_g0, tok_g1, dp, z2);
    k_scan<<<BB*EE, 256, 0, stream>>>(tok_e0, tok_e1, tok_c0, tok_c1, slot_tok, kept0);
    k_aux<<<1, 64, 0, stream>>>(dp, z2, kept0, out + (size_t)NT*DD);
    dim3 g1((HH+63)/64, CAP/64, BB*EE);
    k_ffn1<<<g1, 256, 0, stream>>>(xg, w1, b1, mult_bias, slot_tok, act);
    dim3 g2(DD/64, CAP/64, BB*EE);
    k_ffn2<<<g2, 256, 0, stream>>>(act, w2, b2, eo);
    k_combine<<<NT, 256, 0, stream>>>(x, eo, tok_e0, tok_e1, tok_c0, tok_c1,
                                      tok_g0, tok_g1, ln_g, ln_b, out);
}

// Round 2
// 436.321 us; speedup vs baseline: 2.5575x; 2.5575x over previous
//
#include <hip/hip_runtime.h>
#include <hip/hip_bf16.h>
#include <math.h>

#define BB 4
#define NN 2048
#define DD 512
#define EE 8
#define HH 1365
#define H2 2730
#define CAP 320
#define NT (BB*NN)   // 8192
#define KP2 1408     // K padded for FFN2 (and act leading dim)
#define NW1 2816     // w1t rows per expert: 1408 u + 1408 g

typedef __bf16 bf16_t;
typedef __bf16 bf16x8 __attribute__((ext_vector_type(8)));
typedef float f32x4 __attribute__((ext_vector_type(4)));

// ---------------- helpers ----------------
__device__ __forceinline__ float gelu_exact(float x){
    return 0.5f * x * (1.0f + erff(x * 0.70710678118654752f));
}
__device__ __forceinline__ unsigned rotl32(unsigned x, int d){ return (x<<d)|(x>>(32-d)); }
__device__ __forceinline__ void tf_round(unsigned &x0, unsigned &x1, int r){
    x0 += x1; x1 = rotl32(x1, r); x1 ^= x0;
}
// jax.random.uniform(key(42), (2,4,2048))[1].ravel()[t]
__device__ float threefry_u01_second(unsigned t){
    const unsigned ks0 = 0u, ks1 = 42u, ks2 = 0x1BD11BDAu ^ 42u;
    unsigned x0 = t, x1 = t + 8192u;
    x0 += ks0; x1 += ks1;
    tf_round(x0,x1,13); tf_round(x0,x1,15); tf_round(x0,x1,26); tf_round(x0,x1,6);
    x0 += ks1; x1 += ks2 + 1u;
    tf_round(x0,x1,17); tf_round(x0,x1,29); tf_round(x0,x1,16); tf_round(x0,x1,24);
    x0 += ks2; x1 += ks0 + 2u;
    tf_round(x0,x1,13); tf_round(x0,x1,15); tf_round(x0,x1,26); tf_round(x0,x1,6);
    x0 += ks0; x1 += ks1 + 3u;
    tf_round(x0,x1,17); tf_round(x0,x1,29); tf_round(x0,x1,16); tf_round(x0,x1,24);
    x0 += ks1; x1 += ks2 + 4u;
    tf_round(x0,x1,13); tf_round(x0,x1,15); tf_round(x0,x1,26); tf_round(x0,x1,6);
    x0 += ks2; x1 += ks0 + 5u;
    unsigned bits = (x1 >> 9) | 0x3f800000u;
    return __uint_as_float(bits) - 1.0f;
}

// ---------------- small kernels ----------------
__global__ void k_init(int* slot_tok, int* tok_c0, int* tok_c1, float* dp, float* z2){
    int i = blockIdx.x*256 + threadIdx.x;
    if (i < BB*EE*CAP) slot_tok[i] = -1;
    if (i < NT){ tok_c0[i] = -1; tok_c1[i] = -1; }
    if (i < BB*EE) dp[i] = 0.f;
    if (i == 0) z2[0] = 0.f;
}

// rmsnorm -> bf16 tokens; block NT writes the zero row
__global__ void k_rms_bf16(const float* __restrict__ x, const float* __restrict__ g,
                           bf16_t* __restrict__ xgb){
    int t = blockIdx.x;
    if (t == NT){
        #pragma unroll
        for (int i=0;i<2;i++) xgb[(size_t)NT*DD + threadIdx.x + i*256] = (bf16_t)0.f;
        return;
    }
    const float* row = x + (size_t)t * DD;
    float v[2]; float s = 0.f;
    #pragma unroll
    for (int i=0;i<2;i++){ v[i] = row[threadIdx.x + i*256]; s += v[i]*v[i]; }
    __shared__ float red[4];
    #pragma unroll
    for (int off=32; off; off>>=1) s += __shfl_down(s, off);
    if ((threadIdx.x & 63)==0) red[threadIdx.x>>6] = s;
    __syncthreads();
    float ss = red[0]+red[1]+red[2]+red[3];
    float nrm = fmaxf(sqrtf(ss), 1e-12f);
    float scale = 22.62741699796952f / nrm;   // sqrt(512)
    #pragma unroll
    for (int i=0;i<2;i++){
        int d = threadIdx.x + i*256;
        xgb[(size_t)t*DD + d] = (bf16_t)(v[i] * scale * g[d]);
    }
}

// gating with inline rmsnorm (exact f32 routing)
__global__ void k_gate(const float* __restrict__ x, const float* __restrict__ png,
                       const float* __restrict__ gw,
                       int* tok_e0, int* tok_e1, float* tok_g0, float* tok_g1,
                       float* dp, float* z2){
    int wave = threadIdx.x >> 6;
    int lane = threadIdx.x & 63;
    int t = blockIdx.x*4 + wave;
    int b = t / NN;
    const float* row = x + (size_t)t*DD;
    float xv[8]; float ss = 0.f;
    #pragma unroll
    for (int i=0;i<8;i++){ xv[i] = row[lane + i*64]; ss += xv[i]*xv[i]; }
    #pragma unroll
    for (int off=32; off; off>>=1) ss += __shfl_xor(ss, off);
    float scale = 22.62741699796952f / fmaxf(sqrtf(ss), 1e-12f);
    float acc[EE];
    #pragma unroll
    for (int e=0;e<EE;e++) acc[e]=0.f;
    #pragma unroll
    for (int i=0;i<8;i++){
        int k = lane + i*64;
        float v = xv[i] * scale * png[k];
        const float* w = gw + k*EE;
        #pragma unroll
        for (int e=0;e<EE;e++) acc[e] = fmaf(v, w[e], acc[e]);
    }
    #pragma unroll
    for (int off=32; off; off>>=1){
        #pragma unroll
        for (int e=0;e<EE;e++) acc[e] += __shfl_down(acc[e], off);
    }
    __shared__ float s_raw[4][EE];
    __shared__ float s_z2[4];
    if (lane==0){
        float mx = acc[0];
        #pragma unroll
        for (int e=1;e<EE;e++) mx = fmaxf(mx, acc[e]);
        float p[EE]; float se=0.f;
        #pragma unroll
        for (int e=0;e<EE;e++){ p[e] = expf(acc[e]-mx); se += p[e]; }
        float inv = 1.f/se;
        #pragma unroll
        for (int e=0;e<EE;e++) p[e] *= inv;
        float z = mx + logf(se);
        int i0=0;
        #pragma unroll
        for (int e=1;e<EE;e++) if (p[e] > p[i0]) i0=e;
        int i1 = (i0==0)?1:0;
        #pragma unroll
        for (int e=0;e<EE;e++){ if (e==i0) continue; if (p[e] > p[i1]) i1=e; }
        float g0=p[i0], g1=p[i1];
        float denom = fmaxf(g0+g1, 1e-9f);
        g0/=denom; g1/=denom;
        float prob = threefry_u01_second((unsigned)t);
        bool route1 = prob < (g1 * 5.0f);       // g1 / 0.2
        tok_e0[t] = i0;
        tok_e1[t] = route1 ? i1 : -1;
        tok_g0[t] = g0;
        tok_g1[t] = g1;
        #pragma unroll
        for (int e=0;e<EE;e++) s_raw[wave][e] = p[e];
        s_z2[wave] = z*z;
    }
    __syncthreads();
    if (threadIdx.x < EE){
        float sum = s_raw[0][threadIdx.x]+s_raw[1][threadIdx.x]+s_raw[2][threadIdx.x]+s_raw[3][threadIdx.x];
        atomicAdd(&dp[b*EE + threadIdx.x], sum);
    }
    if (threadIdx.x == EE) atomicAdd(z2, s_z2[0]+s_z2[1]+s_z2[2]+s_z2[3]);
}

__global__ void k_scan(const int* __restrict__ tok_e0, const int* __restrict__ tok_e1,
                       int* tok_c0, int* tok_c1, int* slot_tok, int* kept0cnt){
    int be = blockIdx.x;
    int b = be >> 3, e = be & 7;
    int tid = threadIdx.x;      // 256 threads, 8 tokens each
    int n0 = tid * 8;
    int base_t = b*NN;
    int m0=0, m1=0;
    for (int i=0;i<8;i++){
        int t = base_t + n0 + i;
        m0 += (tok_e0[t]==e);
        m1 += (tok_e1[t]==e);
    }
    __shared__ int s[256];
    s[tid] = m0 | (m1<<16);
    __syncthreads();
    for (int off=1; off<256; off<<=1){
        int v = 0;
        if (tid >= off) v = s[tid-off];
        __syncthreads();
        if (tid >= off) s[tid] += v;
        __syncthreads();
    }
    int incl = s[tid];
    int total = s[255];
    int p0 = (incl & 0xffff) - m0;
    int p1 = (incl >> 16) - m1;
    int t0 = total & 0xffff;
    int kept0 = min(t0, CAP);
    int c0 = p0, c1 = p1;
    for (int i=0;i<8;i++){
        int n = n0 + i;
        int t = base_t + n;
        if (tok_e0[t]==e){
            int pos = c0++;
            if (pos < CAP){ tok_c0[t] = pos; slot_tok[be*CAP + pos] = n; }
        }
        if (tok_e1[t]==e){
            int pos = kept0 + c1++;
            if (pos < CAP){ tok_c1[t] = pos; slot_tok[be*CAP + pos] = n; }
        }
    }
    if (tid==0) kept0cnt[be] = kept0;
}

__global__ void k_aux(const float* dp, const float* z2, const int* kept0cnt, float* out_aux){
    if (threadIdx.x==0 && blockIdx.x==0){
        float bal = 0.f;
        for (int i=0;i<BB*EE;i++){
            float dpm = dp[i] / (float)NN;
            float d1  = (float)kept0cnt[i] / (float)NN;
            bal += dpm * d1;
        }
        bal = bal / (float)(BB*EE) * (float)(EE*EE);
        float zl = z2[0] / (float)(BB*NN);
        out_aux[0] = 0.01f * bal + 0.001f * zl;
    }
}

// ---------------- weight prep (transpose + cast) ----------------
// w1 [e][512][2730] f32 -> w1t [e][2816][512] bf16 ; rows 0..1407 = u cols, 1408.. = g cols
__global__ void k_w1t(const float* __restrict__ w1, bf16_t* __restrict__ w1t){
    __shared__ float T[32][33];
    int n0 = blockIdx.x * 32;
    int k0 = blockIdx.y * 32;
    int e  = blockIdx.z;
    int tx = threadIdx.x & 31;
    int tg = threadIdx.x >> 5;   // 0..7
    bool half = (n0 >= KP2);
    int nlim = half ? (KP2 + HH) : HH;
    int hoff = half ? (HH - KP2) : 0;
    #pragma unroll
    for (int i=0;i<4;i++){
        int kk = tg + i*8;
        int n = n0 + tx;
        float v = 0.f;
        if (n < nlim) v = w1[((size_t)e*DD + k0 + kk)*H2 + n + hoff];
        T[kk][tx] = v;
    }
    __syncthreads();
    #pragma unroll
    for (int i=0;i<4;i++){
        int nn = tg + i*8;
        w1t[((size_t)e*NW1 + n0 + nn)*DD + k0 + tx] = (bf16_t)T[tx][nn];
    }
}

// w2 [e][1365][512] f32 -> w2t [e][512][1408] bf16 (K padded with zeros)
__global__ void k_w2t(const float* __restrict__ w2, bf16_t* __restrict__ w2t){
    __shared__ float T[32][33];
    int k0 = blockIdx.x * 32;
    int n0 = blockIdx.y * 32;
    int e  = blockIdx.z;
    int tx = threadIdx.x & 31;
    int tg = threadIdx.x >> 5;
    #pragma unroll
    for (int i=0;i<4;i++){
        int kk = tg + i*8;
        float v = 0.f;
        if (k0 + kk < HH) v = w2[((size_t)e*HH + k0 + kk)*DD + n0 + tx];
        T[kk][tx] = v;
    }
    __syncthreads();
    #pragma unroll
    for (int i=0;i<4;i++){
        int nn = tg + i*8;
        w2t[((size_t)e*DD + n0 + nn)*KP2 + k0 + tx] = (bf16_t)T[tx][nn];
    }
}

// ---------------- MFMA FFN kernels (LDS-free, direct-fragment) ----------------
// actb[be*CAP+m][KP2] = geglu(xg @ w1) bf16
__global__ __launch_bounds__(256) void k_ffn1_mfma(
    const bf16_t* __restrict__ xgb, const bf16_t* __restrict__ w1t,
    const float* __restrict__ b1, const float* __restrict__ mb,
    const int* __restrict__ slot_tok, bf16_t* __restrict__ actb)
{
    int bx = blockIdx.x;            // m_blk + 5*b : consecutive blocks share W tile
    int m_blk = bx % 5, b = bx / 5;
    int n_blk = blockIdx.y;         // 0..10 (128 cols each)
    int e = blockIdx.z;
    int be = b*EE + e;
    int lane = threadIdx.x & 63, wave = threadIdx.x >> 6;
    int quad = lane >> 4, col = lane & 15;
    int wm = (wave & 1) * 32, wn = (wave >> 1) * 64;

    const bf16_t* aptr[2];
    #pragma unroll
    for (int mi=0; mi<2; mi++){
        int m = m_blk*64 + wm + mi*16 + col;
        int slot = slot_tok[be*CAP + m];
        int row = (slot >= 0) ? (b*NN + slot) : NT;
        aptr[mi] = xgb + (size_t)row*DD + quad*8;
    }
    const bf16_t* bptrU[4]; const bf16_t* bptrG[4];
    #pragma unroll
    for (int ni=0; ni<4; ni++){
        int n = n_blk*128 + wn + ni*16 + col;
        bptrU[ni] = w1t + ((size_t)e*NW1 + n)*DD + quad*8;
        bptrG[ni] = w1t + ((size_t)e*NW1 + KP2 + n)*DD + quad*8;
    }
    f32x4 accU[2][4], accG[2][4];
    #pragma unroll
    for (int mi=0;mi<2;mi++)
        #pragma unroll
        for (int ni=0;ni<4;ni++){
            accU[mi][ni] = (f32x4){0.f,0.f,0.f,0.f};
            accG[mi][ni] = (f32x4){0.f,0.f,0.f,0.f};
        }

    #pragma unroll 4
    for (int kc=0; kc<DD; kc+=32){
        bf16x8 a[2], bu[4], bg[4];
        #pragma unroll
        for (int mi=0;mi<2;mi++) a[mi] = *(const bf16x8*)(aptr[mi] + kc);
        #pragma unroll
        for (int ni=0;ni<4;ni++){
            bu[ni] = *(const bf16x8*)(bptrU[ni] + kc);
            bg[ni] = *(const bf16x8*)(bptrG[ni] + kc);
        }
        #pragma unroll
        for (int mi=0;mi<2;mi++)
            #pragma unroll
            for (int ni=0;ni<4;ni++){
                accU[mi][ni] = __builtin_amdgcn_mfma_f32_16x16x32_bf16(a[mi], bu[ni], accU[mi][ni], 0,0,0);
                accG[mi][ni] = __builtin_amdgcn_mfma_f32_16x16x32_bf16(a[mi], bg[ni], accG[mi][ni], 0,0,0);
            }
    }
    // epilogue: act = (u+bu) * gelu(g+bg) * mb, zero for pad cols
    #pragma unroll
    for (int ni=0; ni<4; ni++){
        int h = n_blk*128 + wn + ni*16 + col;
        bool valid = (h < HH);
        float bu_ = valid ? b1[e*H2 + h] : 0.f;
        float bg_ = valid ? b1[e*H2 + HH + h] : 0.f;
        float mb_ = valid ? mb[e*HH + h] : 0.f;
        #pragma unroll
        for (int mi=0; mi<2; mi++){
            #pragma unroll
            for (int r=0; r<4; r++){
                int m = m_blk*64 + wm + mi*16 + quad*4 + r;
                float v = 0.f;
                if (valid){
                    float u = accU[mi][ni][r] + bu_;
                    float g = accG[mi][ni][r] + bg_;
                    v = u * gelu_exact(g) * mb_;
                }
                actb[((size_t)be*CAP + m)*KP2 + h] = (bf16_t)v;
            }
        }
    }
}

// eo[be*CAP+m][512] = act @ w2 + b2 (f32)
__global__ __launch_bounds__(256) void k_ffn2_mfma(
    const bf16_t* __restrict__ actb, const bf16_t* __restrict__ w2t,
    const float* __restrict__ b2, float* __restrict__ eo)
{
    int bx = blockIdx.x;            // m_blk + 5*b
    int m_blk = bx % 5, b = bx / 5;
    int n_blk = blockIdx.y;         // 0..3
    int e = blockIdx.z;
    int be = b*EE + e;
    int lane = threadIdx.x & 63, wave = threadIdx.x >> 6;
    int quad = lane >> 4, col = lane & 15;
    int wm = (wave & 1) * 32, wn = (wave >> 1) * 64;

    const bf16_t* aptr[2];
    #pragma unroll
    for (int mi=0; mi<2; mi++){
        int m = m_blk*64 + wm + mi*16 + col;
        aptr[mi] = actb + ((size_t)be*CAP + m)*KP2 + quad*8;
    }
    const bf16_t* bptr[4];
    #pragma unroll
    for (int ni=0; ni<4; ni++){
        int n = n_blk*128 + wn + ni*16 + col;
        bptr[ni] = w2t + ((size_t)e*DD + n)*KP2 + quad*8;
    }
    f32x4 acc[2][4];
    #pragma unroll
    for (int mi=0;mi<2;mi++)
        #pragma unroll
        for (int ni=0;ni<4;ni++) acc[mi][ni] = (f32x4){0.f,0.f,0.f,0.f};

    #pragma unroll 4
    for (int kc=0; kc<KP2; kc+=32){
        bf16x8 a[2], bv[4];
        #pragma unroll
        for (int mi=0;mi<2;mi++) a[mi] = *(const bf16x8*)(aptr[mi] + kc);
        #pragma unroll
        for (int ni=0;ni<4;ni++) bv[ni] = *(const bf16x8*)(bptr[ni] + kc);
        #pragma unroll
        for (int mi=0;mi<2;mi++)
            #pragma unroll
            for (int ni=0;ni<4;ni++)
                acc[mi][ni] = __builtin_amdgcn_mfma_f32_16x16x32_bf16(a[mi], bv[ni], acc[mi][ni], 0,0,0);
    }
    #pragma unroll
    for (int ni=0; ni<4; ni++){
        int d = n_blk*128 + wn + ni*16 + col;
        float bb = b2[e*DD + d];
        #pragma unroll
        for (int mi=0; mi<2; mi++){
            #pragma unroll
            for (int r=0; r<4; r++){
                int m = m_blk*64 + wm + mi*16 + quad*4 + r;
                eo[((size_t)be*CAP + m)*DD + d] = acc[mi][ni][r] + bb;
            }
        }
    }
}

__global__ void k_combine(const float* __restrict__ x, const float* __restrict__ eo,
        const int* __restrict__ tok_e0, const int* __restrict__ tok_e1,
        const int* __restrict__ tok_c0, const int* __restrict__ tok_c1,
        const float* __restrict__ tok_g0, const float* __restrict__ tok_g1,
        const float* __restrict__ ln_g, const float* __restrict__ ln_b,
        float* __restrict__ out){
    int t = blockIdx.x;
    int b = t / NN;
    int e0 = tok_e0[t], c0 = tok_c0[t];
    int e1 = tok_e1[t], c1 = tok_c1[t];
    float g0 = tok_g0[t], g1 = tok_g1[t];
    const float* r0 = (c0>=0) ? eo + (((size_t)(b*EE+e0))*CAP + c0)*DD : nullptr;
    const float* r1 = (e1>=0 && c1>=0) ? eo + (((size_t)(b*EE+e1))*CAP + c1)*DD : nullptr;
    float y[2]; float s=0.f, s2=0.f;
    #pragma unroll
    for (int i=0;i<2;i++){
        int d = threadIdx.x + i*256;
        float v = x[(size_t)t*DD + d];
        if (r0) v = fmaf(g0, r0[d], v);
        if (r1) v = fmaf(g1, r1[d], v);
        y[i]=v; s+=v; s2+=v*v;
    }
    __shared__ float rs[4], rs2[4];
    #pragma unroll
    for (int off=32; off; off>>=1){ s+=__shfl_down(s,off); s2+=__shfl_down(s2,off); }
    if ((threadIdx.x&63)==0){ rs[threadIdx.x>>6]=s; rs2[threadIdx.x>>6]=s2; }
    __syncthreads();
    float mu  = (rs[0]+rs[1]+rs[2]+rs[3]) * (1.0f/512.0f);
    float var = (rs2[0]+rs2[1]+rs2[2]+rs2[3]) * (1.0f/512.0f) - mu*mu;
    float inv = rsqrtf(var + 1e-5f);
    #pragma unroll
    for (int i=0;i<2;i++){
        int d = threadIdx.x + i*256;
        out[(size_t)t*DD + d] = (y[i]-mu)*inv*ln_g[d] + ln_b[d];
    }
}

extern "C" void kernel_launch(void* const* d_in, const int* in_sizes, int n_in,
                              void* d_out, int out_size, void* d_ws, size_t ws_size,
                              hipStream_t stream) {
    const float* x         = (const float*)d_in[0];
    const float* gate_w    = (const float*)d_in[1];
    const float* prenorm_g = (const float*)d_in[2];
    const float* w1        = (const float*)d_in[3];
    const float* b1        = (const float*)d_in[4];
    const float* mult_bias = (const float*)d_in[5];
    const float* w2        = (const float*)d_in[6];
    const float* b2        = (const float*)d_in[7];
    const float* ln_g      = (const float*)d_in[8];
    const float* ln_b      = (const float*)d_in[9];
    float* out = (float*)d_out;

    char* p = (char*)d_ws;
    bf16_t* xgb = (bf16_t*)p; p += (size_t)(NT+1)*DD*2;
    bf16_t* w1t = (bf16_t*)p; p += (size_t)EE*NW1*DD*2;
    bf16_t* w2t = (bf16_t*)p; p += (size_t)EE*DD*KP2*2;
    bf16_t* actb = (bf16_t*)p; p += (size_t)BB*EE*CAP*KP2*2;
    float* eo  = (float*)p; p += (size_t)BB*EE*CAP*DD*4;
    int* slot_tok = (int*)p; p += BB*EE*CAP*4;
    int* tok_e0 = (int*)p; p += NT*4;
    int* tok_e1 = (int*)p; p += NT*4;
    int* tok_c0 = (int*)p; p += NT*4;
    int* tok_c1 = (int*)p; p += NT*4;
    float* tok_g0 = (float*)p; p += NT*4;
    float* tok_g1 = (float*)p; p += NT*4;
    float* dp = (float*)p; p += BB*EE*4;
    float* z2 = (float*)p; p += 4;
    int* kept0 = (int*)p; p += BB*EE*4;

    k_init<<<40, 256, 0, stream>>>(slot_tok, tok_c0, tok_c1, dp, z2);
    // weight prep (independent of routing)
    k_w1t<<<dim3(NW1/32, DD/32, EE), 256, 0, stream>>>(w1, w1t);
    k_w2t<<<dim3(KP2/32, DD/32, EE), 256, 0, stream>>>(w2, w2t);
    k_rms_bf16<<<NT+1, 256, 0, stream>>>(x, prenorm_g, xgb);
    k_gate<<<NT/4, 256, 0, stream>>>(x, prenorm_g, gate_w, tok_e0, tok_e1, tok_g0, tok_g1, dp, z2);
    k_scan<<<BB*EE, 256, 0, stream>>>(tok_e0, tok_e1, tok_c0, tok_c1, slot_tok, kept0);
    k_aux<<<1, 64, 0, stream>>>(dp, z2, kept0, out + (size_t)NT*DD);
    k_ffn1_mfma<<<dim3(20, KP2/128, EE), 256, 0, stream>>>(xgb, w1t, b1, mult_bias, slot_tok, actb);
    k_ffn2_mfma<<<dim3(20, DD/128, EE), 256, 0, stream>>>(actb, w2t, b2, eo);
    k_combine<<<NT, 256, 0, stream>>>(x, eo, tok_e0, tok_e1, tok_c0, tok_c1,
                                      tok_g0, tok_g1, ln_g, ln_b, out);
}

// Round 3
// 309.915 us; speedup vs baseline: 3.6007x; 1.4079x over previous
//
#include <hip/hip_runtime.h>
#include <hip/hip_bf16.h>
#include <math.h>

#define BB 4
#define NN 2048
#define DD 512
#define EE 8
#define HH 1365
#define H2 2730
#define CAP 320
#define NT (BB*NN)   // 8192
#define KP2 1408     // K padded for FFN2 (act leading dim)
#define NW1 2816     // w1t rows per expert: 1408 u + 1408 g
#define ME 1280      // rows per expert = BB*CAP

typedef __bf16 bf16_t;
typedef __bf16 bf16x8 __attribute__((ext_vector_type(8)));
typedef float f32x4 __attribute__((ext_vector_type(4)));

// ---------------- helpers ----------------
__device__ __forceinline__ float gelu_exact(float x){
    return 0.5f * x * (1.0f + erff(x * 0.70710678118654752f));
}
__device__ __forceinline__ void gl2lds16(const void* g, void* s){
    // per-lane global source, wave-uniform LDS dest; lane i lands at s + i*16
    __builtin_amdgcn_global_load_lds((const __attribute__((address_space(1))) unsigned int*)g,
                                     (__attribute__((address_space(3))) unsigned int*)s,
                                     16, 0, 0);
}
__device__ __forceinline__ unsigned rotl32(unsigned x, int d){ return (x<<d)|(x>>(32-d)); }
__device__ __forceinline__ void tf_round(unsigned &x0, unsigned &x1, int r){
    x0 += x1; x1 = rotl32(x1, r); x1 ^= x0;
}
// jax.random.uniform(key(42), (2,4,2048))[1].ravel()[t]
__device__ float threefry_u01_second(unsigned t){
    const unsigned ks0 = 0u, ks1 = 42u, ks2 = 0x1BD11BDAu ^ 42u;
    unsigned x0 = t, x1 = t + 8192u;
    x0 += ks0; x1 += ks1;
    tf_round(x0,x1,13); tf_round(x0,x1,15); tf_round(x0,x1,26); tf_round(x0,x1,6);
    x0 += ks1; x1 += ks2 + 1u;
    tf_round(x0,x1,17); tf_round(x0,x1,29); tf_round(x0,x1,16); tf_round(x0,x1,24);
    x0 += ks2; x1 += ks0 + 2u;
    tf_round(x0,x1,13); tf_round(x0,x1,15); tf_round(x0,x1,26); tf_round(x0,x1,6);
    x0 += ks0; x1 += ks1 + 3u;
    tf_round(x0,x1,17); tf_round(x0,x1,29); tf_round(x0,x1,16); tf_round(x0,x1,24);
    x0 += ks1; x1 += ks2 + 4u;
    tf_round(x0,x1,13); tf_round(x0,x1,15); tf_round(x0,x1,26); tf_round(x0,x1,6);
    x0 += ks2; x1 += ks0 + 5u;
    unsigned bits = (x1 >> 9) | 0x3f800000u;
    return __uint_as_float(bits) - 1.0f;
}

// ---------------- gate: rmsnorm + softmax + top2 + stochastic route ----------------
// grid NN+1 blocks x 256 (4 waves = 4 tokens); block NN writes the zero row.
__global__ void k_gate(const float* __restrict__ x, const float* __restrict__ png,
                       const float* __restrict__ gw, bf16_t* __restrict__ xgb,
                       int* __restrict__ tok_e0, int* __restrict__ tok_e1,
                       float* __restrict__ tok_g0, float* __restrict__ tok_g1,
                       int* __restrict__ tok_c0, int* __restrict__ tok_c1,
                       float* __restrict__ dpPart, float* __restrict__ z2Part){
    if (blockIdx.x == NN){
        xgb[(size_t)NT*DD + threadIdx.x]       = (bf16_t)0.f;
        xgb[(size_t)NT*DD + threadIdx.x + 256] = (bf16_t)0.f;
        return;
    }
    int wave = threadIdx.x >> 6;
    int lane = threadIdx.x & 63;
    int t = blockIdx.x*4 + wave;
    const float* row = x + (size_t)t*DD;
    float xv[8]; float ss = 0.f;
    #pragma unroll
    for (int i=0;i<8;i++){ xv[i] = row[lane + i*64]; ss += xv[i]*xv[i]; }
    #pragma unroll
    for (int off=32; off; off>>=1) ss += __shfl_xor(ss, off);
    float scale = 22.62741699796952f / fmaxf(sqrtf(ss), 1e-12f);
    float acc[EE];
    #pragma unroll
    for (int e=0;e<EE;e++) acc[e]=0.f;
    #pragma unroll
    for (int i=0;i<8;i++){
        int k = lane + i*64;
        float v = xv[i] * scale * png[k];
        xgb[(size_t)t*DD + k] = (bf16_t)v;
        const float* w = gw + k*EE;
        #pragma unroll
        for (int e=0;e<EE;e++) acc[e] = fmaf(v, w[e], acc[e]);
    }
    #pragma unroll
    for (int off=32; off; off>>=1){
        #pragma unroll
        for (int e=0;e<EE;e++) acc[e] += __shfl_down(acc[e], off);
    }
    __shared__ float s_raw[4][EE];
    __shared__ float s_z2[4];
    if (lane==0){
        float mx = acc[0];
        #pragma unroll
        for (int e=1;e<EE;e++) mx = fmaxf(mx, acc[e]);
        float p[EE]; float se=0.f;
        #pragma unroll
        for (int e=0;e<EE;e++){ p[e] = expf(acc[e]-mx); se += p[e]; }
        float inv = 1.f/se;
        #pragma unroll
        for (int e=0;e<EE;e++) p[e] *= inv;
        float z = mx + logf(se);
        int i0=0;
        #pragma unroll
        for (int e=1;e<EE;e++) if (p[e] > p[i0]) i0=e;
        int i1 = (i0==0)?1:0;
        #pragma unroll
        for (int e=0;e<EE;e++){ if (e==i0) continue; if (p[e] > p[i1]) i1=e; }
        float g0=p[i0], g1=p[i1];
        float denom = fmaxf(g0+g1, 1e-9f);
        g0/=denom; g1/=denom;
        float prob = threefry_u01_second((unsigned)t);
        bool route1 = prob < (g1 * 5.0f);       // g1 / 0.2
        tok_e0[t] = i0;
        tok_e1[t] = route1 ? i1 : -1;
        tok_g0[t] = g0;
        tok_g1[t] = g1;
        tok_c0[t] = -1;
        tok_c1[t] = -1;
        #pragma unroll
        for (int e=0;e<EE;e++) s_raw[wave][e] = p[e];
        s_z2[wave] = z*z;
    }
    __syncthreads();
    if (threadIdx.x < EE){
        float sum = s_raw[0][threadIdx.x]+s_raw[1][threadIdx.x]+s_raw[2][threadIdx.x]+s_raw[3][threadIdx.x];
        dpPart[threadIdx.x*(size_t)NN + blockIdx.x] = sum;
    }
    if (threadIdx.x == EE) z2Part[blockIdx.x] = s_z2[0]+s_z2[1]+s_z2[2]+s_z2[3];
}

// ---------------- scan: capacity positions + slot->token map ----------------
__global__ void k_scan(const int* __restrict__ tok_e0, const int* __restrict__ tok_e1,
                       int* __restrict__ tok_c0, int* __restrict__ tok_c1,
                       int* __restrict__ slot_tok, int* __restrict__ kept0cnt){
    int be = blockIdx.x;            // b*8+e
    int b = be >> 3, e = be & 7;
    int tid = threadIdx.x;          // 256 threads, 8 tokens each
    int sbase = (e*BB + b)*CAP;     // slot layout [e][b][cap]
    for (int i=tid; i<CAP; i+=256) slot_tok[sbase + i] = -1;
    __syncthreads();
    int n0 = tid * 8;
    int base_t = b*NN;
    int m0=0, m1=0;
    for (int i=0;i<8;i++){
        int t = base_t + n0 + i;
        m0 += (tok_e0[t]==e);
        m1 += (tok_e1[t]==e);
    }
    __shared__ int s[256];
    s[tid] = m0 | (m1<<16);
    __syncthreads();
    for (int off=1; off<256; off<<=1){
        int v = 0;
        if (tid >= off) v = s[tid-off];
        __syncthreads();
        if (tid >= off) s[tid] += v;
        __syncthreads();
    }
    int incl = s[tid];
    int total = s[255];
    int p0 = (incl & 0xffff) - m0;
    int p1 = (incl >> 16) - m1;
    int t0 = total & 0xffff;
    int kept0 = min(t0, CAP);
    int c0 = p0, c1 = p1;
    for (int i=0;i<8;i++){
        int n = n0 + i;
        int t = base_t + n;
        if (tok_e0[t]==e){
            int pos = c0++;
            if (pos < CAP){ tok_c0[t] = pos; slot_tok[sbase + pos] = t; }
        }
        if (tok_e1[t]==e){
            int pos = kept0 + c1++;
            if (pos < CAP){ tok_c1[t] = pos; slot_tok[sbase + pos] = t; }
        }
    }
    if (tid==0) kept0cnt[be] = kept0;
}

// ---------------- aux loss reduce ----------------
__global__ void k_aux(const float* __restrict__ dpPart, const float* __restrict__ z2Part,
                      const int* __restrict__ kept0cnt, float* __restrict__ out_aux){
    __shared__ float sdp[32][9];
    __shared__ float sz[256];
    int tid = threadIdx.x;
    float za = 0.f;
    for (int i=tid; i<NN; i+=256) za += z2Part[i];
    sz[tid] = za; __syncthreads();
    for (int off=128; off; off>>=1){ if (tid<off) sz[tid]+=sz[tid+off]; __syncthreads(); }
    int seg = tid >> 3, off8 = tid & 7;
    int b = seg >> 3, e = seg & 7;
    float a = 0.f;
    for (int j=off8; j<512; j+=8) a += dpPart[e*(size_t)NN + b*512 + j];
    sdp[seg][off8] = a;
    __syncthreads();
    if (tid == 0){
        float z2t = sz[0];
        float bal = 0.f;
        for (int sgi=0; sgi<32; sgi++){
            float d = 0.f;
            #pragma unroll
            for (int k=0;k<8;k++) d += sdp[sgi][k];
            float d1 = (float)kept0cnt[sgi] / (float)NN;
            bal += (d / (float)NN) * d1;
        }
        bal = bal / 32.f * 64.f;
        out_aux[0] = 0.01f * bal + 0.001f * (z2t / (float)NT);
    }
}

// ---------------- weight prep (transpose + cast) ----------------
__global__ void k_w1t(const float* __restrict__ w1, bf16_t* __restrict__ w1t){
    __shared__ float T[32][33];
    int n0 = blockIdx.x * 32;
    int k0 = blockIdx.y * 32;
    int e  = blockIdx.z;
    int tx = threadIdx.x & 31;
    int tg = threadIdx.x >> 5;
    bool half = (n0 >= KP2);
    int nlim = half ? (KP2 + HH) : HH;
    int hoff = half ? (HH - KP2) : 0;
    #pragma unroll
    for (int i=0;i<4;i++){
        int kk = tg + i*8;
        int n = n0 + tx;
        float v = 0.f;
        if (n < nlim) v = w1[((size_t)e*DD + k0 + kk)*H2 + n + hoff];
        T[kk][tx] = v;
    }
    __syncthreads();
    #pragma unroll
    for (int i=0;i<4;i++){
        int nn = tg + i*8;
        w1t[((size_t)e*NW1 + n0 + nn)*DD + k0 + tx] = (bf16_t)T[tx][nn];
    }
}

__global__ void k_w2t(const float* __restrict__ w2, bf16_t* __restrict__ w2t){
    __shared__ float T[32][33];
    int k0 = blockIdx.x * 32;
    int n0 = blockIdx.y * 32;
    int e  = blockIdx.z;
    int tx = threadIdx.x & 31;
    int tg = threadIdx.x >> 5;
    #pragma unroll
    for (int i=0;i<4;i++){
        int kk = tg + i*8;
        float v = 0.f;
        if (k0 + kk < HH) v = w2[((size_t)e*HH + k0 + kk)*DD + n0 + tx];
        T[kk][tx] = v;
    }
    __syncthreads();
    #pragma unroll
    for (int i=0;i<4;i++){
        int nn = tg + i*8;
        w2t[((size_t)e*DD + n0 + nn)*KP2 + k0 + tx] = (bf16_t)T[tx][nn];
    }
}

// ---------------- FFN1: LDS-staged MFMA GEMM + fused GEGLU ----------------
// block: 128 M x 64 N(h), u+g fused. grid 1D: id = e + 8*(m_blk + 10*n_blk)
__global__ __launch_bounds__(256) void k_ffn1_mfma(
    const bf16_t* __restrict__ xgb, const bf16_t* __restrict__ w1t,
    const float* __restrict__ b1, const float* __restrict__ mb,
    const int* __restrict__ slot_tok, bf16_t* __restrict__ actb)
{
    int bid = blockIdx.x;
    int e = bid & 7;
    int r = bid >> 3;
    int m_blk = r % 10, n_blk = r / 10;   // 0..9, 0..21
    int lane = threadIdx.x & 63, wave = threadIdx.x >> 6;
    int quad = lane >> 4, col = lane & 15;

    __shared__ __align__(16) bf16_t sA[8*512];
    __shared__ __align__(16) bf16_t sBu[4*512];
    __shared__ __align__(16) bf16_t sBg[4*512];

    // staging: 16 chunks of 1KB, 4 per wave (ids wave+4i)
    const bf16_t* gptr[4];
    bf16_t* sptr[4];
    #pragma unroll
    for (int i=0;i<4;i++){
        int id = wave + i*4;
        if (id < 8){
            int slot = slot_tok[e*ME + m_blk*128 + id*16 + col];
            int row = (slot >= 0) ? slot : NT;
            gptr[i] = xgb + (size_t)row*DD + quad*8;
            sptr[i] = sA + id*512;
        } else if (id < 12){
            int n = n_blk*64 + (id-8)*16 + col;
            gptr[i] = w1t + ((size_t)e*NW1 + n)*DD + quad*8;
            sptr[i] = sBu + (id-8)*512;
        } else {
            int n = n_blk*64 + (id-12)*16 + col;
            gptr[i] = w1t + ((size_t)e*NW1 + KP2 + n)*DD + quad*8;
            sptr[i] = sBg + (id-12)*512;
        }
    }

    f32x4 accU[2][4], accG[2][4];
    #pragma unroll
    for (int mi=0;mi<2;mi++)
        #pragma unroll
        for (int ni=0;ni<4;ni++){
            accU[mi][ni] = (f32x4){0.f,0.f,0.f,0.f};
            accG[mi][ni] = (f32x4){0.f,0.f,0.f,0.f};
        }

    for (int ks=0; ks<DD/32; ks++){
        #pragma unroll
        for (int i=0;i<4;i++){ gl2lds16(gptr[i], sptr[i]); gptr[i] += 32; }
        __syncthreads();
        bf16x8 a[2], bu[4], bg[4];
        #pragma unroll
        for (int mi=0;mi<2;mi++) a[mi] = *(const bf16x8*)(sA + (wave*2+mi)*512 + lane*8);
        #pragma unroll
        for (int ni=0;ni<4;ni++){
            bu[ni] = *(const bf16x8*)(sBu + ni*512 + lane*8);
            bg[ni] = *(const bf16x8*)(sBg + ni*512 + lane*8);
        }
        #pragma unroll
        for (int mi=0;mi<2;mi++)
            #pragma unroll
            for (int ni=0;ni<4;ni++){
                accU[mi][ni] = __builtin_amdgcn_mfma_f32_16x16x32_bf16(a[mi], bu[ni], accU[mi][ni], 0,0,0);
                accG[mi][ni] = __builtin_amdgcn_mfma_f32_16x16x32_bf16(a[mi], bg[ni], accG[mi][ni], 0,0,0);
            }
        __syncthreads();
    }
    #pragma unroll
    for (int ni=0; ni<4; ni++){
        int h = n_blk*64 + ni*16 + col;
        bool valid = (h < HH);
        float bu_ = valid ? b1[e*H2 + h] : 0.f;
        float bg_ = valid ? b1[e*H2 + HH + h] : 0.f;
        float mb_ = valid ? mb[e*HH + h] : 0.f;
        #pragma unroll
        for (int mi=0; mi<2; mi++){
            int mrow = m_blk*128 + wave*32 + mi*16 + quad*4;
            #pragma unroll
            for (int rr=0; rr<4; rr++){
                float v = 0.f;
                if (valid){
                    float u = accU[mi][ni][rr] + bu_;
                    float g = accG[mi][ni][rr] + bg_;
                    v = u * gelu_exact(g) * mb_;
                }
                actb[((size_t)e*ME + mrow + rr)*KP2 + h] = (bf16_t)v;
            }
        }
    }
}

// ---------------- FFN2: LDS-staged MFMA GEMM ----------------
// block: 128 M x 64 N(d). grid 1D: id = e + 8*(m_blk + 10*n_blk), n_blk 0..7
__global__ __launch_bounds__(256) void k_ffn2_mfma(
    const bf16_t* __restrict__ actb, const bf16_t* __restrict__ w2t,
    const float* __restrict__ b2, float* __restrict__ eo)
{
    int bid = blockIdx.x;
    int e = bid & 7;
    int r = bid >> 3;
    int m_blk = r % 10, n_blk = r / 10;   // 0..9, 0..7
    int lane = threadIdx.x & 63, wave = threadIdx.x >> 6;
    int quad = lane >> 4, col = lane & 15;

    __shared__ __align__(16) bf16_t sA[8*512];
    __shared__ __align__(16) bf16_t sB[4*512];

    // 12 chunks, 3 per wave (ids wave+4i, i<3)
    const bf16_t* gptr[3];
    bf16_t* sptr[3];
    #pragma unroll
    for (int i=0;i<3;i++){
        int id = wave + i*4;
        if (id < 8){
            int mrow = e*ME + m_blk*128 + id*16 + col;
            gptr[i] = actb + (size_t)mrow*KP2 + quad*8;
            sptr[i] = sA + id*512;
        } else {
            int n = n_blk*64 + (id-8)*16 + col;
            gptr[i] = w2t + ((size_t)e*DD + n)*KP2 + quad*8;
            sptr[i] = sB + (id-8)*512;
        }
    }

    f32x4 acc[2][4];
    #pragma unroll
    for (int mi=0;mi<2;mi++)
        #pragma unroll
        for (int ni=0;ni<4;ni++) acc[mi][ni] = (f32x4){0.f,0.f,0.f,0.f};

    for (int ks=0; ks<KP2/32; ks++){
        #pragma unroll
        for (int i=0;i<3;i++){ gl2lds16(gptr[i], sptr[i]); gptr[i] += 32; }
        __syncthreads();
        bf16x8 a[2], bv[4];
        #pragma unroll
        for (int mi=0;mi<2;mi++) a[mi] = *(const bf16x8*)(sA + (wave*2+mi)*512 + lane*8);
        #pragma unroll
        for (int ni=0;ni<4;ni++) bv[ni] = *(const bf16x8*)(sB + ni*512 + lane*8);
        #pragma unroll
        for (int mi=0;mi<2;mi++)
            #pragma unroll
            for (int ni=0;ni<4;ni++)
                acc[mi][ni] = __builtin_amdgcn_mfma_f32_16x16x32_bf16(a[mi], bv[ni], acc[mi][ni], 0,0,0);
        __syncthreads();
    }
    #pragma unroll
    for (int ni=0; ni<4; ni++){
        int d = n_blk*64 + ni*16 + col;
        float bb = b2[e*DD + d];
        #pragma unroll
        for (int mi=0; mi<2; mi++){
            int mrow = m_blk*128 + wave*32 + mi*16 + quad*4;
            #pragma unroll
            for (int rr=0; rr<4; rr++)
                eo[((size_t)e*ME + mrow + rr)*DD + d] = acc[mi][ni][rr] + bb;
        }
    }
}

// ---------------- combine + residual + LayerNorm ----------------
__global__ void k_combine(const float* __restrict__ x, const float* __restrict__ eo,
        const int* __restrict__ tok_e0, const int* __restrict__ tok_e1,
        const int* __restrict__ tok_c0, const int* __restrict__ tok_c1,
        const float* __restrict__ tok_g0, const float* __restrict__ tok_g1,
        const float* __restrict__ ln_g, const float* __restrict__ ln_b,
        float* __restrict__ out){
    int t = blockIdx.x;
    int b = t / NN;
    int e0 = tok_e0[t], c0 = tok_c0[t];
    int e1 = tok_e1[t], c1 = tok_c1[t];
    float g0 = tok_g0[t], g1 = tok_g1[t];
    const float* r0 = (c0>=0) ? eo + ((size_t)(e0*ME + b*CAP + c0))*DD : nullptr;
    const float* r1 = (e1>=0 && c1>=0) ? eo + ((size_t)(e1*ME + b*CAP + c1))*DD : nullptr;
    float y[2]; float s=0.f, s2=0.f;
    #pragma unroll
    for (int i=0;i<2;i++){
        int d = threadIdx.x + i*256;
        float v = x[(size_t)t*DD + d];
        if (r0) v = fmaf(g0, r0[d], v);
        if (r1) v = fmaf(g1, r1[d], v);
        y[i]=v; s+=v; s2+=v*v;
    }
    __shared__ float rs[4], rs2[4];
    #pragma unroll
    for (int off=32; off; off>>=1){ s+=__shfl_down(s,off); s2+=__shfl_down(s2,off); }
    if ((threadIdx.x&63)==0){ rs[threadIdx.x>>6]=s; rs2[threadIdx.x>>6]=s2; }
    __syncthreads();
    float mu  = (rs[0]+rs[1]+rs[2]+rs[3]) * (1.0f/512.0f);
    float var = (rs2[0]+rs2[1]+rs2[2]+rs2[3]) * (1.0f/512.0f) - mu*mu;
    float inv = rsqrtf(var + 1e-5f);
    #pragma unroll
    for (int i=0;i<2;i++){
        int d = threadIdx.x + i*256;
        out[(size_t)t*DD + d] = (y[i]-mu)*inv*ln_g[d] + ln_b[d];
    }
}

extern "C" void kernel_launch(void* const* d_in, const int* in_sizes, int n_in,
                              void* d_out, int out_size, void* d_ws, size_t ws_size,
                              hipStream_t stream) {
    const float* x         = (const float*)d_in[0];
    const float* gate_w    = (const float*)d_in[1];
    const float* prenorm_g = (const float*)d_in[2];
    const float* w1        = (const float*)d_in[3];
    const float* b1        = (const float*)d_in[4];
    const float* mult_bias = (const float*)d_in[5];
    const float* w2        = (const float*)d_in[6];
    const float* b2        = (const float*)d_in[7];
    const float* ln_g      = (const float*)d_in[8];
    const float* ln_b      = (const float*)d_in[9];
    float* out = (float*)d_out;

    char* p = (char*)d_ws;
    bf16_t* xgb = (bf16_t*)p; p += (size_t)(NT+1)*DD*2;
    bf16_t* w1t = (bf16_t*)p; p += (size_t)EE*NW1*DD*2;
    bf16_t* w2t = (bf16_t*)p; p += (size_t)EE*DD*KP2*2;
    bf16_t* actb = (bf16_t*)p; p += (size_t)EE*ME*KP2*2;
    float* eo  = (float*)p; p += (size_t)EE*ME*DD*4;
    int* slot_tok = (int*)p; p += EE*BB*CAP*4;
    int* tok_e0 = (int*)p; p += NT*4;
    int* tok_e1 = (int*)p; p += NT*4;
    int* tok_c0 = (int*)p; p += NT*4;
    int* tok_c1 = (int*)p; p += NT*4;
    float* tok_g0 = (float*)p; p += NT*4;
    float* tok_g1 = (float*)p; p += NT*4;
    float* dpPart = (float*)p; p += EE*NN*4;
    float* z2Part = (float*)p; p += NN*4;
    int* kept0 = (int*)p; p += BB*EE*4;

    k_w1t<<<dim3(NW1/32, DD/32, EE), 256, 0, stream>>>(w1, w1t);
    k_w2t<<<dim3(KP2/32, DD/32, EE), 256, 0, stream>>>(w2, w2t);
    k_gate<<<NN+1, 256, 0, stream>>>(x, prenorm_g, gate_w, xgb,
                                     tok_e0, tok_e1, tok_g0, tok_g1,
                                     tok_c0, tok_c1, dpPart, z2Part);
    k_scan<<<BB*EE, 256, 0, stream>>>(tok_e0, tok_e1, tok_c0, tok_c1, slot_tok, kept0);
    k_aux<<<1, 256, 0, stream>>>(dpPart, z2Part, kept0, out + (size_t)NT*DD);
    k_ffn1_mfma<<<EE*10*22, 256, 0, stream>>>(xgb, w1t, b1, mult_bias, slot_tok, actb);
    k_ffn2_mfma<<<EE*10*8, 256, 0, stream>>>(actb, w2t, b2, eo);
    k_combine<<<NT, 256, 0, stream>>>(x, eo, tok_e0, tok_e1, tok_c0, tok_c1,
                                      tok_g0, tok_g1, ln_g, ln_b, out);
}

// Round 4
// 272.566 us; speedup vs baseline: 4.0941x; 1.1370x over previous
//
#include <hip/hip_runtime.h>
#include <hip/hip_bf16.h>
#include <math.h>

#define BB 4
#define NN 2048
#define DD 512
#define EE 8
#define HH 1365
#define H2 2730
#define CAP 320
#define NT (BB*NN)   // 8192
#define KP2 1408     // padded K for FFN2
#define NW1 2816     // w1t rows per expert: 1408 u + 1408 g
#define ME 1280      // rows per expert = BB*CAP
#define KS1 16       // K-steps FFN1 (512/32)
#define KS2 44       // K-steps FFN2 (1408/32)

typedef __bf16 bf16_t;
typedef __bf16 bf16x4 __attribute__((ext_vector_type(4)));
typedef __bf16 bf16x8 __attribute__((ext_vector_type(8)));
typedef float f32x4 __attribute__((ext_vector_type(4)));

// ---------------- helpers ----------------
__device__ __forceinline__ float gelu_exact(float x){
    return 0.5f * x * (1.0f + erff(x * 0.70710678118654752f));
}
__device__ __forceinline__ void gl2lds16(const void* g, void* s){
    // per-lane global source address; LDS dest = uniform base + lane*16
    __builtin_amdgcn_global_load_lds((const __attribute__((address_space(1))) unsigned int*)g,
                                     (__attribute__((address_space(3))) unsigned int*)s,
                                     16, 0, 0);
}
__device__ __forceinline__ unsigned rotl32(unsigned x, int d){ return (x<<d)|(x>>(32-d)); }
__device__ __forceinline__ void tf_round(unsigned &x0, unsigned &x1, int r){
    x0 += x1; x1 = rotl32(x1, r); x1 ^= x0;
}
// jax.random.uniform(key(42), (2,4,2048))[1].ravel()[t]
__device__ float threefry_u01_second(unsigned t){
    const unsigned ks0 = 0u, ks1 = 42u, ks2 = 0x1BD11BDAu ^ 42u;
    unsigned x0 = t, x1 = t + 8192u;
    x0 += ks0; x1 += ks1;
    tf_round(x0,x1,13); tf_round(x0,x1,15); tf_round(x0,x1,26); tf_round(x0,x1,6);
    x0 += ks1; x1 += ks2 + 1u;
    tf_round(x0,x1,17); tf_round(x0,x1,29); tf_round(x0,x1,16); tf_round(x0,x1,24);
    x0 += ks2; x1 += ks0 + 2u;
    tf_round(x0,x1,13); tf_round(x0,x1,15); tf_round(x0,x1,26); tf_round(x0,x1,6);
    x0 += ks0; x1 += ks1 + 3u;
    tf_round(x0,x1,17); tf_round(x0,x1,29); tf_round(x0,x1,16); tf_round(x0,x1,24);
    x0 += ks1; x1 += ks2 + 4u;
    tf_round(x0,x1,13); tf_round(x0,x1,15); tf_round(x0,x1,26); tf_round(x0,x1,6);
    x0 += ks2; x1 += ks0 + 5u;
    unsigned bits = (x1 >> 9) | 0x3f800000u;
    return __uint_as_float(bits) - 1.0f;
}

// ---------------- gate: rmsnorm + softmax + top2 + stochastic route ----------------
__global__ void k_gate(const float* __restrict__ x, const float* __restrict__ png,
                       const float* __restrict__ gw, bf16_t* __restrict__ xgb,
                       int* __restrict__ tok_e0, int* __restrict__ tok_e1,
                       float* __restrict__ tok_g0, float* __restrict__ tok_g1,
                       int* __restrict__ tok_c0, int* __restrict__ tok_c1,
                       float* __restrict__ dpPart, float* __restrict__ z2Part){
    if (blockIdx.x == NN){
        xgb[(size_t)NT*DD + threadIdx.x]       = (bf16_t)0.f;
        xgb[(size_t)NT*DD + threadIdx.x + 256] = (bf16_t)0.f;
        return;
    }
    int wave = threadIdx.x >> 6;
    int lane = threadIdx.x & 63;
    int t = blockIdx.x*4 + wave;
    const float* row = x + (size_t)t*DD;
    float xv[8]; float ss = 0.f;
    #pragma unroll
    for (int i=0;i<8;i++){ xv[i] = row[lane + i*64]; ss += xv[i]*xv[i]; }
    #pragma unroll
    for (int off=32; off; off>>=1) ss += __shfl_xor(ss, off);
    float scale = 22.62741699796952f / fmaxf(sqrtf(ss), 1e-12f);
    float acc[EE];
    #pragma unroll
    for (int e=0;e<EE;e++) acc[e]=0.f;
    #pragma unroll
    for (int i=0;i<8;i++){
        int k = lane + i*64;
        float v = xv[i] * scale * png[k];
        xgb[(size_t)t*DD + k] = (bf16_t)v;
        const float* w = gw + k*EE;
        #pragma unroll
        for (int e=0;e<EE;e++) acc[e] = fmaf(v, w[e], acc[e]);
    }
    #pragma unroll
    for (int off=32; off; off>>=1){
        #pragma unroll
        for (int e=0;e<EE;e++) acc[e] += __shfl_down(acc[e], off);
    }
    __shared__ float s_raw[4][EE];
    __shared__ float s_z2[4];
    if (lane==0){
        float mx = acc[0];
        #pragma unroll
        for (int e=1;e<EE;e++) mx = fmaxf(mx, acc[e]);
        float p[EE]; float se=0.f;
        #pragma unroll
        for (int e=0;e<EE;e++){ p[e] = expf(acc[e]-mx); se += p[e]; }
        float inv = 1.f/se;
        #pragma unroll
        for (int e=0;e<EE;e++) p[e] *= inv;
        float z = mx + logf(se);
        int i0=0;
        #pragma unroll
        for (int e=1;e<EE;e++) if (p[e] > p[i0]) i0=e;
        int i1 = (i0==0)?1:0;
        #pragma unroll
        for (int e=0;e<EE;e++){ if (e==i0) continue; if (p[e] > p[i1]) i1=e; }
        float g0=p[i0], g1=p[i1];
        float denom = fmaxf(g0+g1, 1e-9f);
        g0/=denom; g1/=denom;
        float prob = threefry_u01_second((unsigned)t);
        bool route1 = prob < (g1 * 5.0f);       // g1 / 0.2
        tok_e0[t] = i0;
        tok_e1[t] = route1 ? i1 : -1;
        tok_g0[t] = g0;
        tok_g1[t] = g1;
        tok_c0[t] = -1;
        tok_c1[t] = -1;
        #pragma unroll
        for (int e=0;e<EE;e++) s_raw[wave][e] = p[e];
        s_z2[wave] = z*z;
    }
    __syncthreads();
    if (threadIdx.x < EE){
        float sum = s_raw[0][threadIdx.x]+s_raw[1][threadIdx.x]+s_raw[2][threadIdx.x]+s_raw[3][threadIdx.x];
        dpPart[threadIdx.x*(size_t)NN + blockIdx.x] = sum;
    }
    if (threadIdx.x == EE) z2Part[blockIdx.x] = s_z2[0]+s_z2[1]+s_z2[2]+s_z2[3];
}

// ---------------- scan: capacity positions + slot->token map ----------------
__global__ void k_scan(const int* __restrict__ tok_e0, const int* __restrict__ tok_e1,
                       int* __restrict__ tok_c0, int* __restrict__ tok_c1,
                       int* __restrict__ slot_tok, int* __restrict__ kept0cnt){
    int be = blockIdx.x;            // b*8+e
    int b = be >> 3, e = be & 7;
    int tid = threadIdx.x;
    int sbase = (e*BB + b)*CAP;     // slot layout [e][b][cap]
    for (int i=tid; i<CAP; i+=256) slot_tok[sbase + i] = -1;
    __syncthreads();
    int n0 = tid * 8;
    int base_t = b*NN;
    int m0=0, m1=0;
    for (int i=0;i<8;i++){
        int t = base_t + n0 + i;
        m0 += (tok_e0[t]==e);
        m1 += (tok_e1[t]==e);
    }
    __shared__ int s[256];
    s[tid] = m0 | (m1<<16);
    __syncthreads();
    for (int off=1; off<256; off<<=1){
        int v = 0;
        if (tid >= off) v = s[tid-off];
        __syncthreads();
        if (tid >= off) s[tid] += v;
        __syncthreads();
    }
    int incl = s[tid];
    int total = s[255];
    int p0 = (incl & 0xffff) - m0;
    int p1 = (incl >> 16) - m1;
    int t0 = total & 0xffff;
    int kept0 = min(t0, CAP);
    int c0 = p0, c1 = p1;
    for (int i=0;i<8;i++){
        int n = n0 + i;
        int t = base_t + n;
        if (tok_e0[t]==e){
            int pos = c0++;
            if (pos < CAP){ tok_c0[t] = pos; slot_tok[sbase + pos] = t; }
        }
        if (tok_e1[t]==e){
            int pos = kept0 + c1++;
            if (pos < CAP){ tok_c1[t] = pos; slot_tok[sbase + pos] = t; }
        }
    }
    if (tid==0) kept0cnt[be] = kept0;
}

// ---------------- aux loss reduce ----------------
__global__ void k_aux(const float* __restrict__ dpPart, const float* __restrict__ z2Part,
                      const int* __restrict__ kept0cnt, float* __restrict__ out_aux){
    __shared__ float sdp[32][9];
    __shared__ float sz[256];
    int tid = threadIdx.x;
    float za = 0.f;
    for (int i=tid; i<NN; i+=256) za += z2Part[i];
    sz[tid] = za; __syncthreads();
    for (int off=128; off; off>>=1){ if (tid<off) sz[tid]+=sz[tid+off]; __syncthreads(); }
    int seg = tid >> 3, off8 = tid & 7;
    int b = seg >> 3, e = seg & 7;
    float a = 0.f;
    for (int j=off8; j<512; j+=8) a += dpPart[e*(size_t)NN + b*512 + j];
    sdp[seg][off8] = a;
    __syncthreads();
    if (tid == 0){
        float z2t = sz[0];
        float bal = 0.f;
        for (int sgi=0; sgi<32; sgi++){
            float d = 0.f;
            #pragma unroll
            for (int k=0;k<8;k++) d += sdp[sgi][k];
            float d1 = (float)kept0cnt[sgi] / (float)NN;
            bal += (d / (float)NN) * d1;
        }
        bal = bal / 32.f * 64.f;
        out_aux[0] = 0.01f * bal + 0.001f * (z2t / (float)NT);
    }
}

// ---------------- weight prep: K-tiled layouts ----------------
// w1t[e][ks=16][n=2816][32]: n<1408 -> u col n (valid n<1365); n>=1408 -> g col (n-1408)
__global__ void k_w1t(const float* __restrict__ w1, bf16_t* __restrict__ w1t){
    __shared__ float T[32][33];
    int n0 = blockIdx.x * 32;
    int ks = blockIdx.y;
    int e  = blockIdx.z;
    int tx = threadIdx.x & 31;
    int tg = threadIdx.x >> 5;
    int n = n0 + tx;
    #pragma unroll
    for (int i=0;i<4;i++){
        int kk = tg + i*8;
        int k = ks*32 + kk;
        float v = 0.f;
        if (n < KP2){ if (n < HH) v = w1[((size_t)e*DD + k)*H2 + n]; }
        else { int h = n - KP2; if (h < HH) v = w1[((size_t)e*DD + k)*H2 + HH + h]; }
        T[kk][tx] = v;
    }
    __syncthreads();
    int rr = threadIdx.x >> 3, s = threadIdx.x & 7;
    bf16x4 o;
    #pragma unroll
    for (int j=0;j<4;j++) o[j] = (bf16_t)T[s*4+j][rr];
    size_t off = (((size_t)e*KS1 + ks)*NW1 + n0 + rr)*32 + s*4;
    *(bf16x4*)(w1t + off) = o;
}

// w2t[e][ks=44][d=512][32], K padded 1365->1408 with zeros
__global__ void k_w2t(const float* __restrict__ w2, bf16_t* __restrict__ w2t){
    __shared__ float T[32][33];
    int n0 = blockIdx.x * 32;
    int ks = blockIdx.y;
    int e  = blockIdx.z;
    int tx = threadIdx.x & 31;
    int tg = threadIdx.x >> 5;
    #pragma unroll
    for (int i=0;i<4;i++){
        int kk = tg + i*8;
        int k = ks*32 + kk;
        float v = 0.f;
        if (k < HH) v = w2[((size_t)e*HH + k)*DD + n0 + tx];
        T[kk][tx] = v;
    }
    __syncthreads();
    int rr = threadIdx.x >> 3, s = threadIdx.x & 7;
    bf16x4 o;
    #pragma unroll
    for (int j=0;j<4;j++) o[j] = (bf16_t)T[s*4+j][rr];
    size_t off = (((size_t)e*KS2 + ks)*DD + n0 + rr)*32 + s*4;
    *(bf16x4*)(w2t + off) = o;
}

// ---------------- FFN1: 128M x 128h tile, K-tiled staging ----------------
// grid: bid = e + 8*(mblk + 10*hb); mblk 0..9, hb 0..10
__global__ __launch_bounds__(256,2) void k_ffn1_mfma(
    const bf16_t* __restrict__ xgb, const bf16_t* __restrict__ w1t,
    const float* __restrict__ b1, const float* __restrict__ mbias,
    const int* __restrict__ slot_tok, bf16_t* __restrict__ actb)
{
    int bid = blockIdx.x;
    int e = bid & 7;
    int r = bid >> 3;
    int mblk = r % 10, hb = r / 10;
    int lane = threadIdx.x & 63, wave = threadIdx.x >> 6;
    int quad = lane >> 4, col = lane & 15;
    int wx = wave & 1, wy = wave >> 1;

    __shared__ __align__(16) bf16_t sA[8*512];    // 8KB: A chunks 0-7 (16 m-rows each)
    __shared__ __align__(16) bf16_t sB[16*512];   // 16KB: u chunks 0-7, g chunks 8-15

    const bf16_t* gsrc[6];
    bf16_t* sdst[6];
    int gstep[6];
    const size_t w1t_e = (size_t)e*KS1*NW1*32;
    #pragma unroll
    for (int i=0;i<6;i++){
        int id = wave + 4*i;
        if (id < 8){
            int m = mblk*128 + id*16 + col;
            int slot = slot_tok[e*ME + m];
            int row = (slot >= 0) ? slot : NT;
            gsrc[i] = xgb + (size_t)row*DD + quad*8;
            sdst[i] = sA + id*512;
            gstep[i] = 32;
        } else if (id < 16){
            int n = hb*128 + (id-8)*16 + col;
            gsrc[i] = w1t + w1t_e + (size_t)n*32 + quad*8;
            sdst[i] = sB + (id-8)*512;
            gstep[i] = NW1*32;
        } else {
            int n = KP2 + hb*128 + (id-16)*16 + col;
            gsrc[i] = w1t + w1t_e + (size_t)n*32 + quad*8;
            sdst[i] = sB + (id-8)*512;
            gstep[i] = NW1*32;
        }
    }

    f32x4 accU[4][4], accG[4][4];
    #pragma unroll
    for (int mi=0;mi<4;mi++)
        #pragma unroll
        for (int ni=0;ni<4;ni++){
            accU[mi][ni] = (f32x4){0.f,0.f,0.f,0.f};
            accG[mi][ni] = (f32x4){0.f,0.f,0.f,0.f};
        }

    for (int ks=0; ks<KS1; ks++){
        #pragma unroll
        for (int i=0;i<6;i++){ gl2lds16(gsrc[i], sdst[i]); gsrc[i] += gstep[i]; }
        __syncthreads();
        bf16x8 a[4], bu[4], bg[4];
        #pragma unroll
        for (int mi=0;mi<4;mi++) a[mi] = *(const bf16x8*)(sA + (wx*4+mi)*512 + lane*8);
        #pragma unroll
        for (int ni=0;ni<4;ni++){
            bu[ni] = *(const bf16x8*)(sB + (wy*4+ni)*512 + lane*8);
            bg[ni] = *(const bf16x8*)(sB + (8+wy*4+ni)*512 + lane*8);
        }
        #pragma unroll
        for (int mi=0;mi<4;mi++)
            #pragma unroll
            for (int ni=0;ni<4;ni++){
                accU[mi][ni] = __builtin_amdgcn_mfma_f32_16x16x32_bf16(a[mi], bu[ni], accU[mi][ni], 0,0,0);
                accG[mi][ni] = __builtin_amdgcn_mfma_f32_16x16x32_bf16(a[mi], bg[ni], accG[mi][ni], 0,0,0);
            }
        __syncthreads();
    }

    // epilogue -> actb[e][ks2][m][32]
    const size_t actb_e = (size_t)e*KS2*ME*32;
    #pragma unroll
    for (int ni=0; ni<4; ni++){
        int h = hb*128 + wy*64 + ni*16 + col;
        bool valid = (h < HH);
        float bu_ = valid ? b1[e*H2 + h] : 0.f;
        float bg_ = valid ? b1[e*H2 + HH + h] : 0.f;
        float mb_ = valid ? mbias[e*HH + h] : 0.f;
        int ks2 = h >> 5, kl = h & 31;
        #pragma unroll
        for (int mi=0; mi<4; mi++){
            int m = mblk*128 + wx*64 + mi*16 + quad*4;
            bf16_t* base = actb + actb_e + ((size_t)ks2*ME + m)*32 + kl;
            #pragma unroll
            for (int rr=0; rr<4; rr++){
                float v = 0.f;
                if (valid){
                    float u = accU[mi][ni][rr] + bu_;
                    float g = accG[mi][ni][rr] + bg_;
                    v = u * gelu_exact(g) * mb_;
                }
                base[rr*32] = (bf16_t)v;
            }
        }
    }
}

// ---------------- FFN2: 128M x 128d tile, K-tiled staging ----------------
// grid: bid = e + 8*(mblk + 10*db); mblk 0..9, db 0..3
__global__ __launch_bounds__(256,4) void k_ffn2_mfma(
    const bf16_t* __restrict__ actb, const bf16_t* __restrict__ w2t,
    const float* __restrict__ b2, float* __restrict__ eo)
{
    int bid = blockIdx.x;
    int e = bid & 7;
    int r = bid >> 3;
    int mblk = r % 10, db = r / 10;
    int lane = threadIdx.x & 63, wave = threadIdx.x >> 6;
    int quad = lane >> 4, col = lane & 15;
    int wx = wave & 1, wy = wave >> 1;

    __shared__ __align__(16) bf16_t sA[8*512];
    __shared__ __align__(16) bf16_t sB[8*512];

    const bf16_t* gsrc[4];
    bf16_t* sdst[4];
    int gstep[4];
    const size_t actb_e = (size_t)e*KS2*ME*32;
    const size_t w2t_e  = (size_t)e*KS2*DD*32;
    #pragma unroll
    for (int i=0;i<4;i++){
        int id = wave + 4*i;
        if (id < 8){
            int m = mblk*128 + id*16 + col;
            gsrc[i] = actb + actb_e + (size_t)m*32 + quad*8;
            sdst[i] = sA + id*512;
            gstep[i] = ME*32;
        } else {
            int d = db*128 + (id-8)*16 + col;
            gsrc[i] = w2t + w2t_e + (size_t)d*32 + quad*8;
            sdst[i] = sB + (id-8)*512;
            gstep[i] = DD*32;
        }
    }

    f32x4 acc[4][4];
    #pragma unroll
    for (int mi=0;mi<4;mi++)
        #pragma unroll
        for (int ni=0;ni<4;ni++) acc[mi][ni] = (f32x4){0.f,0.f,0.f,0.f};

    for (int ks=0; ks<KS2; ks++){
        #pragma unroll
        for (int i=0;i<4;i++){ gl2lds16(gsrc[i], sdst[i]); gsrc[i] += gstep[i]; }
        __syncthreads();
        bf16x8 a[4], bv[4];
        #pragma unroll
        for (int mi=0;mi<4;mi++) a[mi] = *(const bf16x8*)(sA + (wx*4+mi)*512 + lane*8);
        #pragma unroll
        for (int ni=0;ni<4;ni++) bv[ni] = *(const bf16x8*)(sB + (wy*4+ni)*512 + lane*8);
        #pragma unroll
        for (int mi=0;mi<4;mi++)
            #pragma unroll
            for (int ni=0;ni<4;ni++)
                acc[mi][ni] = __builtin_amdgcn_mfma_f32_16x16x32_bf16(a[mi], bv[ni], acc[mi][ni], 0,0,0);
        __syncthreads();
    }

    #pragma unroll
    for (int ni=0; ni<4; ni++){
        int d = db*128 + wy*64 + ni*16 + col;
        float bb = b2[e*DD + d];
        #pragma unroll
        for (int mi=0; mi<4; mi++){
            int m = mblk*128 + wx*64 + mi*16 + quad*4;
            #pragma unroll
            for (int rr=0; rr<4; rr++)
                eo[((size_t)e*ME + m + rr)*DD + d] = acc[mi][ni][rr] + bb;
        }
    }
}

// ---------------- combine + residual + LayerNorm ----------------
__global__ void k_combine(const float* __restrict__ x, const float* __restrict__ eo,
        const int* __restrict__ tok_e0, const int* __restrict__ tok_e1,
        const int* __restrict__ tok_c0, const int* __restrict__ tok_c1,
        const float* __restrict__ tok_g0, const float* __restrict__ tok_g1,
        const float* __restrict__ ln_g, const float* __restrict__ ln_b,
        float* __restrict__ out){
    int t = blockIdx.x;
    int b = t / NN;
    int e0 = tok_e0[t], c0 = tok_c0[t];
    int e1 = tok_e1[t], c1 = tok_c1[t];
    float g0 = tok_g0[t], g1 = tok_g1[t];
    const float* r0 = (c0>=0) ? eo + ((size_t)(e0*ME + b*CAP + c0))*DD : nullptr;
    const float* r1 = (e1>=0 && c1>=0) ? eo + ((size_t)(e1*ME + b*CAP + c1))*DD : nullptr;
    float y[2]; float s=0.f, s2=0.f;
    #pragma unroll
    for (int i=0;i<2;i++){
        int d = threadIdx.x + i*256;
        float v = x[(size_t)t*DD + d];
        if (r0) v = fmaf(g0, r0[d], v);
        if (r1) v = fmaf(g1, r1[d], v);
        y[i]=v; s+=v; s2+=v*v;
    }
    __shared__ float rs[4], rs2[4];
    #pragma unroll
    for (int off=32; off; off>>=1){ s+=__shfl_down(s,off); s2+=__shfl_down(s2,off); }
    if ((threadIdx.x&63)==0){ rs[threadIdx.x>>6]=s; rs2[threadIdx.x>>6]=s2; }
    __syncthreads();
    float mu  = (rs[0]+rs[1]+rs[2]+rs[3]) * (1.0f/512.0f);
    float var = (rs2[0]+rs2[1]+rs2[2]+rs2[3]) * (1.0f/512.0f) - mu*mu;
    float inv = rsqrtf(var + 1e-5f);
    #pragma unroll
    for (int i=0;i<2;i++){
        int d = threadIdx.x + i*256;
        out[(size_t)t*DD + d] = (y[i]-mu)*inv*ln_g[d] + ln_b[d];
    }
}

extern "C" void kernel_launch(void* const* d_in, const int* in_sizes, int n_in,
                              void* d_out, int out_size, void* d_ws, size_t ws_size,
                              hipStream_t stream) {
    const float* x         = (const float*)d_in[0];
    const float* gate_w    = (const float*)d_in[1];
    const float* prenorm_g = (const float*)d_in[2];
    const float* w1        = (const float*)d_in[3];
    const float* b1        = (const float*)d_in[4];
    const float* mult_bias = (const float*)d_in[5];
    const float* w2        = (const float*)d_in[6];
    const float* b2        = (const float*)d_in[7];
    const float* ln_g      = (const float*)d_in[8];
    const float* ln_b      = (const float*)d_in[9];
    float* out = (float*)d_out;

    char* p = (char*)d_ws;
    bf16_t* xgb = (bf16_t*)p; p += (size_t)(NT+1)*DD*2;
    bf16_t* w1t = (bf16_t*)p; p += (size_t)EE*KS1*NW1*32*2;
    bf16_t* w2t = (bf16_t*)p; p += (size_t)EE*KS2*DD*32*2;
    bf16_t* actb = (bf16_t*)p; p += (size_t)EE*KS2*ME*32*2;
    float* eo  = (float*)p; p += (size_t)EE*ME*DD*4;
    int* slot_tok = (int*)p; p += EE*BB*CAP*4;
    int* tok_e0 = (int*)p; p += NT*4;
    int* tok_e1 = (int*)p; p += NT*4;
    int* tok_c0 = (int*)p; p += NT*4;
    int* tok_c1 = (int*)p; p += NT*4;
    float* tok_g0 = (float*)p; p += NT*4;
    float* tok_g1 = (float*)p; p += NT*4;
    float* dpPart = (float*)p; p += EE*NN*4;
    float* z2Part = (float*)p; p += NN*4;
    int* kept0 = (int*)p; p += BB*EE*4;

    k_w1t<<<dim3(NW1/32, KS1, EE), 256, 0, stream>>>(w1, w1t);
    k_w2t<<<dim3(DD/32, KS2, EE), 256, 0, stream>>>(w2, w2t);
    k_gate<<<NN+1, 256, 0, stream>>>(x, prenorm_g, gate_w, xgb,
                                     tok_e0, tok_e1, tok_g0, tok_g1,
                                     tok_c0, tok_c1, dpPart, z2Part);
    k_scan<<<BB*EE, 256, 0, stream>>>(tok_e0, tok_e1, tok_c0, tok_c1, slot_tok, kept0);
    k_aux<<<1, 256, 0, stream>>>(dpPart, z2Part, kept0, out + (size_t)NT*DD);
    k_ffn1_mfma<<<EE*10*11, 256, 0, stream>>>(xgb, w1t, b1, mult_bias, slot_tok, actb);
    k_ffn2_mfma<<<EE*10*4, 256, 0, stream>>>(actb, w2t, b2, eo);
    k_combine<<<NT, 256, 0, stream>>>(x, eo, tok_e0, tok_e1, tok_c0, tok_c1,
                                      tok_g0, tok_g1, ln_g, ln_b, out);
}

// Round 5
// 269.146 us; speedup vs baseline: 4.1461x; 1.0127x over previous
//
#include <hip/hip_runtime.h>
#include <hip/hip_bf16.h>
#include <math.h>

#define BB 4
#define NN 2048
#define DD 512
#define EE 8
#define HH 1365
#define H2 2730
#define CAP 320
#define NT (BB*NN)   // 8192
#define KP2 1408     // padded K for FFN2
#define NW1 2816     // w1t rows per expert: 1408 u + 1408 g
#define ME 1280      // rows per expert = BB*CAP
#define KS1 16       // K-steps FFN1 (512/32)
#define KS2 44       // K-steps FFN2 (1408/32)

typedef __bf16 bf16_t;
typedef __bf16 bf16x4 __attribute__((ext_vector_type(4)));
typedef __bf16 bf16x8 __attribute__((ext_vector_type(8)));
typedef float f32x4 __attribute__((ext_vector_type(4)));

// ---------------- helpers ----------------
__device__ __forceinline__ float gelu_exact(float x){
    return 0.5f * x * (1.0f + erff(x * 0.70710678118654752f));
}
__device__ __forceinline__ void gl2lds16(const void* g, void* s){
    // per-lane global source address; LDS dest = uniform base + lane*16
    __builtin_amdgcn_global_load_lds((const __attribute__((address_space(1))) unsigned int*)g,
                                     (__attribute__((address_space(3))) unsigned int*)s,
                                     16, 0, 0);
}
__device__ __forceinline__ unsigned rotl32(unsigned x, int d){ return (x<<d)|(x>>(32-d)); }
__device__ __forceinline__ void tf_round(unsigned &x0, unsigned &x1, int r){
    x0 += x1; x1 = rotl32(x1, r); x1 ^= x0;
}
// jax.random.uniform(key(42), (2,4,2048))[1].ravel()[t]
__device__ float threefry_u01_second(unsigned t){
    const unsigned ks0 = 0u, ks1 = 42u, ks2 = 0x1BD11BDAu ^ 42u;
    unsigned x0 = t, x1 = t + 8192u;
    x0 += ks0; x1 += ks1;
    tf_round(x0,x1,13); tf_round(x0,x1,15); tf_round(x0,x1,26); tf_round(x0,x1,6);
    x0 += ks1; x1 += ks2 + 1u;
    tf_round(x0,x1,17); tf_round(x0,x1,29); tf_round(x0,x1,16); tf_round(x0,x1,24);
    x0 += ks2; x1 += ks0 + 2u;
    tf_round(x0,x1,13); tf_round(x0,x1,15); tf_round(x0,x1,26); tf_round(x0,x1,6);
    x0 += ks0; x1 += ks1 + 3u;
    tf_round(x0,x1,17); tf_round(x0,x1,29); tf_round(x0,x1,16); tf_round(x0,x1,24);
    x0 += ks1; x1 += ks2 + 4u;
    tf_round(x0,x1,13); tf_round(x0,x1,15); tf_round(x0,x1,26); tf_round(x0,x1,6);
    x0 += ks2; x1 += ks0 + 5u;
    unsigned bits = (x1 >> 9) | 0x3f800000u;
    return __uint_as_float(bits) - 1.0f;
}

// ---------------- prep: gate (rmsnorm+top2+route) & weight transposes, one launch ----
// grid: [0,2048) gate; 2048 zero-row+counter; [2049, 2049+11264) w1t; then 5632 w2t
#define PREP_GATE  2048
#define PREP_W1    (PREP_GATE+1)
#define PREP_W2    (PREP_W1+11264)
__global__ void k_prep(const float* __restrict__ x, const float* __restrict__ png,
                       const float* __restrict__ gw,
                       const float* __restrict__ w1, const float* __restrict__ w2,
                       bf16_t* __restrict__ xgb, bf16_t* __restrict__ w1t, bf16_t* __restrict__ w2t,
                       int* __restrict__ tok_e0, int* __restrict__ tok_e1,
                       float* __restrict__ tok_g0, float* __restrict__ tok_g1,
                       int* __restrict__ tok_c0, int* __restrict__ tok_c1,
                       float* __restrict__ dpPart, float* __restrict__ z2Part,
                       unsigned* __restrict__ scanCnt){
    __shared__ float T[32][33];
    __shared__ float s_raw[4][EE];
    __shared__ float s_z2[4];
    int bid = blockIdx.x;
    if (bid < PREP_GATE){
        int wave = threadIdx.x >> 6;
        int lane = threadIdx.x & 63;
        int t = bid*4 + wave;
        const float* row = x + (size_t)t*DD;
        float xv[8]; float ss = 0.f;
        #pragma unroll
        for (int i=0;i<8;i++){ xv[i] = row[lane + i*64]; ss += xv[i]*xv[i]; }
        #pragma unroll
        for (int off=32; off; off>>=1) ss += __shfl_xor(ss, off);
        float scale = 22.62741699796952f / fmaxf(sqrtf(ss), 1e-12f);
        float acc[EE];
        #pragma unroll
        for (int e=0;e<EE;e++) acc[e]=0.f;
        #pragma unroll
        for (int i=0;i<8;i++){
            int k = lane + i*64;
            float v = xv[i] * scale * png[k];
            xgb[(size_t)t*DD + k] = (bf16_t)v;
            const float* w = gw + k*EE;
            #pragma unroll
            for (int e=0;e<EE;e++) acc[e] = fmaf(v, w[e], acc[e]);
        }
        #pragma unroll
        for (int off=32; off; off>>=1){
            #pragma unroll
            for (int e=0;e<EE;e++) acc[e] += __shfl_down(acc[e], off);
        }
        if (lane==0){
            float mx = acc[0];
            #pragma unroll
            for (int e=1;e<EE;e++) mx = fmaxf(mx, acc[e]);
            float p[EE]; float se=0.f;
            #pragma unroll
            for (int e=0;e<EE;e++){ p[e] = expf(acc[e]-mx); se += p[e]; }
            float inv = 1.f/se;
            #pragma unroll
            for (int e=0;e<EE;e++) p[e] *= inv;
            float z = mx + logf(se);
            int i0=0;
            #pragma unroll
            for (int e=1;e<EE;e++) if (p[e] > p[i0]) i0=e;
            int i1 = (i0==0)?1:0;
            #pragma unroll
            for (int e=0;e<EE;e++){ if (e==i0) continue; if (p[e] > p[i1]) i1=e; }
            float g0=p[i0], g1=p[i1];
            float denom = fmaxf(g0+g1, 1e-9f);
            g0/=denom; g1/=denom;
            float prob = threefry_u01_second((unsigned)t);
            bool route1 = prob < (g1 * 5.0f);       // g1 / 0.2
            tok_e0[t] = i0;
            tok_e1[t] = route1 ? i1 : -1;
            tok_g0[t] = g0;
            tok_g1[t] = g1;
            tok_c0[t] = -1;
            tok_c1[t] = -1;
            #pragma unroll
            for (int e=0;e<EE;e++) s_raw[wave][e] = p[e];
            s_z2[wave] = z*z;
        }
        __syncthreads();
        if (threadIdx.x < EE){
            float sum = s_raw[0][threadIdx.x]+s_raw[1][threadIdx.x]+s_raw[2][threadIdx.x]+s_raw[3][threadIdx.x];
            dpPart[threadIdx.x*(size_t)NN + bid] = sum;
        }
        if (threadIdx.x == EE) z2Part[bid] = s_z2[0]+s_z2[1]+s_z2[2]+s_z2[3];
    } else if (bid == PREP_GATE){
        xgb[(size_t)NT*DD + threadIdx.x]       = (bf16_t)0.f;
        xgb[(size_t)NT*DD + threadIdx.x + 256] = (bf16_t)0.f;
        if (threadIdx.x == 0) scanCnt[0] = 0u;
    } else if (bid < PREP_W2){
        // w1t[e][ks][n=2816][32]
        int f = bid - PREP_W1;
        int n32 = f % 88;
        int ks  = (f / 88) % 16;
        int e   = f / 1408;
        int n0 = n32 * 32;
        int tx = threadIdx.x & 31;
        int tg = threadIdx.x >> 5;
        int n = n0 + tx;
        #pragma unroll
        for (int i=0;i<4;i++){
            int kk = tg + i*8;
            int k = ks*32 + kk;
            float v = 0.f;
            if (n < KP2){ if (n < HH) v = w1[((size_t)e*DD + k)*H2 + n]; }
            else { int h = n - KP2; if (h < HH) v = w1[((size_t)e*DD + k)*H2 + HH + h]; }
            T[kk][tx] = v;
        }
        __syncthreads();
        int rr = threadIdx.x >> 3, s = threadIdx.x & 7;
        bf16x4 o;
        #pragma unroll
        for (int j=0;j<4;j++) o[j] = (bf16_t)T[s*4+j][rr];
        size_t off = (((size_t)e*KS1 + ks)*NW1 + n0 + rr)*32 + s*4;
        *(bf16x4*)(w1t + off) = o;
    } else {
        // w2t[e][ks][d=512][32], K padded with zeros
        int f = bid - PREP_W2;
        int d32 = f % 16;
        int ks  = (f / 16) % 44;
        int e   = f / 704;
        int n0 = d32 * 32;
        int tx = threadIdx.x & 31;
        int tg = threadIdx.x >> 5;
        #pragma unroll
        for (int i=0;i<4;i++){
            int kk = tg + i*8;
            int k = ks*32 + kk;
            float v = 0.f;
            if (k < HH) v = w2[((size_t)e*HH + k)*DD + n0 + tx];
            T[kk][tx] = v;
        }
        __syncthreads();
        int rr = threadIdx.x >> 3, s = threadIdx.x & 7;
        bf16x4 o;
        #pragma unroll
        for (int j=0;j<4;j++) o[j] = (bf16_t)T[s*4+j][rr];
        size_t off = (((size_t)e*KS2 + ks)*DD + n0 + rr)*32 + s*4;
        *(bf16x4*)(w2t + off) = o;
    }
}

// ---------------- scan: capacity positions + slot map; last block computes aux ----
__global__ void k_scan(const int* __restrict__ tok_e0, const int* __restrict__ tok_e1,
                       int* __restrict__ tok_c0, int* __restrict__ tok_c1,
                       int* __restrict__ slot_tok, int* __restrict__ kept0cnt,
                       const float* __restrict__ dpPart, const float* __restrict__ z2Part,
                       unsigned* __restrict__ scanCnt, float* __restrict__ out_aux){
    __shared__ int s[256];
    __shared__ float sdp[32][9];
    __shared__ float sz[256];
    __shared__ bool s_last;
    int be = blockIdx.x;            // b*8+e
    int b = be >> 3, e = be & 7;
    int tid = threadIdx.x;
    int sbase = (e*BB + b)*CAP;     // slot layout [e][b][cap]
    for (int i=tid; i<CAP; i+=256) slot_tok[sbase + i] = -1;
    __syncthreads();
    int n0 = tid * 8;
    int base_t = b*NN;
    int m0=0, m1=0;
    for (int i=0;i<8;i++){
        int t = base_t + n0 + i;
        m0 += (tok_e0[t]==e);
        m1 += (tok_e1[t]==e);
    }
    s[tid] = m0 | (m1<<16);
    __syncthreads();
    for (int off=1; off<256; off<<=1){
        int v = 0;
        if (tid >= off) v = s[tid-off];
        __syncthreads();
        if (tid >= off) s[tid] += v;
        __syncthreads();
    }
    int incl = s[tid];
    int total = s[255];
    int p0 = (incl & 0xffff) - m0;
    int p1 = (incl >> 16) - m1;
    int t0 = total & 0xffff;
    int kept0 = min(t0, CAP);
    int c0 = p0, c1 = p1;
    for (int i=0;i<8;i++){
        int n = n0 + i;
        int t = base_t + n;
        if (tok_e0[t]==e){
            int pos = c0++;
            if (pos < CAP){ tok_c0[t] = pos; slot_tok[sbase + pos] = t; }
        }
        if (tok_e1[t]==e){
            int pos = kept0 + c1++;
            if (pos < CAP){ tok_c1[t] = pos; slot_tok[sbase + pos] = t; }
        }
    }
    if (tid==0) kept0cnt[be] = kept0;
    __threadfence();
    __syncthreads();
    if (tid==0){
        unsigned old = atomicAdd(scanCnt, 1u);
        s_last = (old == (unsigned)(BB*EE - 1));
    }
    __syncthreads();
    if (!s_last) return;
    __threadfence();
    // ---- aux reduction (runs once, in the last-finishing block) ----
    float za = 0.f;
    for (int i=tid; i<NN; i+=256) za += z2Part[i];
    sz[tid] = za; __syncthreads();
    for (int off=128; off; off>>=1){ if (tid<off) sz[tid]+=sz[tid+off]; __syncthreads(); }
    int seg = tid >> 3, off8 = tid & 7;
    int bb2 = seg >> 3, ee2 = seg & 7;
    float a = 0.f;
    for (int j=off8; j<512; j+=8) a += dpPart[ee2*(size_t)NN + bb2*512 + j];
    sdp[seg][off8] = a;
    __syncthreads();
    if (tid == 0){
        float z2t = sz[0];
        float bal = 0.f;
        for (int sgi=0; sgi<32; sgi++){
            float d = 0.f;
            #pragma unroll
            for (int k=0;k<8;k++) d += sdp[sgi][k];
            float d1 = (float)kept0cnt[sgi] / (float)NN;
            bal += (d / (float)NN) * d1;
        }
        bal = bal / 32.f * 64.f;
        out_aux[0] = 0.01f * bal + 0.001f * (z2t / (float)NT);
    }
}

// ---------------- FFN1: 256M x 128h tile, 512 threads (8 waves) ----------------
// grid: bid = e + 8*(mblk + 5*hb); mblk 0..4, hb 0..10
__global__ __launch_bounds__(512,2) void k_ffn1_mfma(
    const bf16_t* __restrict__ xgb, const bf16_t* __restrict__ w1t,
    const float* __restrict__ b1, const float* __restrict__ mbias,
    const int* __restrict__ slot_tok, bf16_t* __restrict__ actb)
{
    int bid = blockIdx.x;
    int e = bid & 7;
    int r = bid >> 3;
    int mblk = r % 5, hb = r / 5;
    int lane = threadIdx.x & 63, wave = threadIdx.x >> 6;   // wave 0..7
    int quad = lane >> 4, col = lane & 15;
    int wm = wave & 3, wn = wave >> 2;                      // 4 M-quarters x 2 h-halves

    __shared__ __align__(16) bf16_t sA[16*512];   // 16KB: 256 m-rows
    __shared__ __align__(16) bf16_t sBu[8*512];   // 8KB: 128 u-rows
    __shared__ __align__(16) bf16_t sBg[8*512];   // 8KB: 128 g-rows

    const bf16_t* gsrc[4];
    bf16_t* sdst[4];
    int gstep[4];
    const size_t w1t_e = (size_t)e*KS1*NW1*32;
    #pragma unroll
    for (int i=0;i<4;i++){
        int id = wave + 8*i;
        if (id < 16){
            int m = mblk*256 + id*16 + col;
            int slot = slot_tok[e*ME + m];
            int row = (slot >= 0) ? slot : NT;
            gsrc[i] = xgb + (size_t)row*DD + quad*8;
            sdst[i] = sA + id*512;
            gstep[i] = 32;
        } else if (id < 24){
            int n = hb*128 + (id-16)*16 + col;
            gsrc[i] = w1t + w1t_e + (size_t)n*32 + quad*8;
            sdst[i] = sBu + (id-16)*512;
            gstep[i] = NW1*32;
        } else {
            int n = KP2 + hb*128 + (id-24)*16 + col;
            gsrc[i] = w1t + w1t_e + (size_t)n*32 + quad*8;
            sdst[i] = sBg + (id-24)*512;
            gstep[i] = NW1*32;
        }
    }

    f32x4 accU[4][4], accG[4][4];
    #pragma unroll
    for (int mi=0;mi<4;mi++)
        #pragma unroll
        for (int ni=0;ni<4;ni++){
            accU[mi][ni] = (f32x4){0.f,0.f,0.f,0.f};
            accG[mi][ni] = (f32x4){0.f,0.f,0.f,0.f};
        }

    for (int ks=0; ks<KS1; ks++){
        #pragma unroll
        for (int i=0;i<4;i++){ gl2lds16(gsrc[i], sdst[i]); gsrc[i] += gstep[i]; }
        __syncthreads();
        bf16x8 a[4], bu[4], bg[4];
        #pragma unroll
        for (int mi=0;mi<4;mi++) a[mi] = *(const bf16x8*)(sA + (wm*4+mi)*512 + lane*8);
        #pragma unroll
        for (int ni=0;ni<4;ni++){
            bu[ni] = *(const bf16x8*)(sBu + (wn*4+ni)*512 + lane*8);
            bg[ni] = *(const bf16x8*)(sBg + (wn*4+ni)*512 + lane*8);
        }
        #pragma unroll
        for (int mi=0;mi<4;mi++)
            #pragma unroll
            for (int ni=0;ni<4;ni++){
                accU[mi][ni] = __builtin_amdgcn_mfma_f32_16x16x32_bf16(a[mi], bu[ni], accU[mi][ni], 0,0,0);
                accG[mi][ni] = __builtin_amdgcn_mfma_f32_16x16x32_bf16(a[mi], bg[ni], accG[mi][ni], 0,0,0);
            }
        __syncthreads();
    }

    // epilogue -> actb[e][ks2][m][32]
    const size_t actb_e = (size_t)e*KS2*ME*32;
    #pragma unroll
    for (int ni=0; ni<4; ni++){
        int h = hb*128 + wn*64 + ni*16 + col;
        bool valid = (h < HH);
        float bu_ = valid ? b1[e*H2 + h] : 0.f;
        float bg_ = valid ? b1[e*H2 + HH + h] : 0.f;
        float mb_ = valid ? mbias[e*HH + h] : 0.f;
        int ks2 = h >> 5, kl = h & 31;
        #pragma unroll
        for (int mi=0; mi<4; mi++){
            int m = mblk*256 + wm*64 + mi*16 + quad*4;
            bf16_t* base = actb + actb_e + ((size_t)ks2*ME + m)*32 + kl;
            #pragma unroll
            for (int rr=0; rr<4; rr++){
                float v = 0.f;
                if (valid){
                    float u = accU[mi][ni][rr] + bu_;
                    float g = accG[mi][ni][rr] + bg_;
                    v = u * gelu_exact(g) * mb_;
                }
                base[rr*32] = (bf16_t)v;
            }
        }
    }
}

// ---------------- FFN2: 128M x 128d tile, split-K=2, bf16 partials ----------------
// grid: bid = e + 8*(mblk + 10*(db + 4*kh)); mblk 0..9, db 0..3, kh 0..1
__global__ __launch_bounds__(256,4) void k_ffn2_mfma(
    const bf16_t* __restrict__ actb, const bf16_t* __restrict__ w2t,
    bf16_t* __restrict__ eoA, bf16_t* __restrict__ eoB)
{
    int bid = blockIdx.x;
    int e = bid & 7;
    int r = bid >> 3;
    int mblk = r % 10;
    int q = r / 10;
    int db = q & 3, kh = q >> 2;
    int lane = threadIdx.x & 63, wave = threadIdx.x >> 6;
    int quad = lane >> 4, col = lane & 15;
    int wx = wave & 1, wy = wave >> 1;

    __shared__ __align__(16) bf16_t sA[8*512];
    __shared__ __align__(16) bf16_t sB[8*512];

    const bf16_t* gsrc[4];
    bf16_t* sdst[4];
    int gstep[4];
    const size_t actb_e = (size_t)e*KS2*ME*32 + (size_t)(kh*22)*ME*32;
    const size_t w2t_e  = (size_t)e*KS2*DD*32 + (size_t)(kh*22)*DD*32;
    #pragma unroll
    for (int i=0;i<4;i++){
        int id = wave + 4*i;
        if (id < 8){
            int m = mblk*128 + id*16 + col;
            gsrc[i] = actb + actb_e + (size_t)m*32 + quad*8;
            sdst[i] = sA + id*512;
            gstep[i] = ME*32;
        } else {
            int d = db*128 + (id-8)*16 + col;
            gsrc[i] = w2t + w2t_e + (size_t)d*32 + quad*8;
            sdst[i] = sB + (id-8)*512;
            gstep[i] = DD*32;
        }
    }

    f32x4 acc[4][4];
    #pragma unroll
    for (int mi=0;mi<4;mi++)
        #pragma unroll
        for (int ni=0;ni<4;ni++) acc[mi][ni] = (f32x4){0.f,0.f,0.f,0.f};

    for (int ks=0; ks<22; ks++){
        #pragma unroll
        for (int i=0;i<4;i++){ gl2lds16(gsrc[i], sdst[i]); gsrc[i] += gstep[i]; }
        __syncthreads();
        bf16x8 a[4], bv[4];
        #pragma unroll
        for (int mi=0;mi<4;mi++) a[mi] = *(const bf16x8*)(sA + (wx*4+mi)*512 + lane*8);
        #pragma unroll
        for (int ni=0;ni<4;ni++) bv[ni] = *(const bf16x8*)(sB + (wy*4+ni)*512 + lane*8);
        #pragma unroll
        for (int mi=0;mi<4;mi++)
            #pragma unroll
            for (int ni=0;ni<4;ni++)
                acc[mi][ni] = __builtin_amdgcn_mfma_f32_16x16x32_bf16(a[mi], bv[ni], acc[mi][ni], 0,0,0);
        __syncthreads();
    }

    bf16_t* eop = kh ? eoB : eoA;
    #pragma unroll
    for (int ni=0; ni<4; ni++){
        int d = db*128 + wy*64 + ni*16 + col;
        #pragma unroll
        for (int mi=0; mi<4; mi++){
            int m = mblk*128 + wx*64 + mi*16 + quad*4;
            #pragma unroll
            for (int rr=0; rr<4; rr++)
                eop[((size_t)e*ME + m + rr)*DD + d] = (bf16_t)acc[mi][ni][rr];
        }
    }
}

// ---------------- combine + residual + LayerNorm (128 thr, float4) ----------------
__global__ void k_combine(const float* __restrict__ x,
        const bf16_t* __restrict__ eoA, const bf16_t* __restrict__ eoB,
        const int* __restrict__ tok_e0, const int* __restrict__ tok_e1,
        const int* __restrict__ tok_c0, const int* __restrict__ tok_c1,
        const float* __restrict__ tok_g0, const float* __restrict__ tok_g1,
        const float* __restrict__ b2,
        const float* __restrict__ ln_g, const float* __restrict__ ln_b,
        float* __restrict__ out){
    int t = blockIdx.x;
    int b = t / NN;
    int tid = threadIdx.x;      // 128
    int i4 = tid*4;
    int e0 = tok_e0[t], c0 = tok_c0[t];
    int e1 = tok_e1[t], c1 = tok_c1[t];
    float g0 = tok_g0[t], g1 = tok_g1[t];
    float4 xv = *(const float4*)(x + (size_t)t*DD + i4);
    float v[4] = {xv.x, xv.y, xv.z, xv.w};
    if (c0 >= 0){
        size_t idx = ((size_t)(e0*ME + b*CAP + c0))*DD + i4;
        bf16x4 pa = *(const bf16x4*)(eoA + idx);
        bf16x4 pb = *(const bf16x4*)(eoB + idx);
        float4 bb = *(const float4*)(b2 + e0*DD + i4);
        v[0] += g0 * ((float)pa[0] + (float)pb[0] + bb.x);
        v[1] += g0 * ((float)pa[1] + (float)pb[1] + bb.y);
        v[2] += g0 * ((float)pa[2] + (float)pb[2] + bb.z);
        v[3] += g0 * ((float)pa[3] + (float)pb[3] + bb.w);
    }
    if (e1 >= 0 && c1 >= 0){
        size_t idx = ((size_t)(e1*ME + b*CAP + c1))*DD + i4;
        bf16x4 pa = *(const bf16x4*)(eoA + idx);
        bf16x4 pb = *(const bf16x4*)(eoB + idx);
        float4 bb = *(const float4*)(b2 + e1*DD + i4);
        v[0] += g1 * ((float)pa[0] + (float)pb[0] + bb.x);
        v[1] += g1 * ((float)pa[1] + (float)pb[1] + bb.y);
        v[2] += g1 * ((float)pa[2] + (float)pb[2] + bb.z);
        v[3] += g1 * ((float)pa[3] + (float)pb[3] + bb.w);
    }
    float s = v[0]+v[1]+v[2]+v[3];
    float s2 = v[0]*v[0]+v[1]*v[1]+v[2]*v[2]+v[3]*v[3];
    __shared__ float rs[2], rs2[2];
    #pragma unroll
    for (int off=32; off; off>>=1){ s += __shfl_down(s,off); s2 += __shfl_down(s2,off); }
    if ((tid&63)==0){ rs[tid>>6]=s; rs2[tid>>6]=s2; }
    __syncthreads();
    float mu  = (rs[0]+rs[1]) * (1.0f/512.0f);
    float var = (rs2[0]+rs2[1]) * (1.0f/512.0f) - mu*mu;
    float inv = rsqrtf(var + 1e-5f);
    float4 gv = *(const float4*)(ln_g + i4);
    float4 bv = *(const float4*)(ln_b + i4);
    float4 o;
    o.x = (v[0]-mu)*inv*gv.x + bv.x;
    o.y = (v[1]-mu)*inv*gv.y + bv.y;
    o.z = (v[2]-mu)*inv*gv.z + bv.z;
    o.w = (v[3]-mu)*inv*gv.w + bv.w;
    *(float4*)(out + (size_t)t*DD + i4) = o;
}

extern "C" void kernel_launch(void* const* d_in, const int* in_sizes, int n_in,
                              void* d_out, int out_size, void* d_ws, size_t ws_size,
                              hipStream_t stream) {
    const float* x         = (const float*)d_in[0];
    const float* gate_w    = (const float*)d_in[1];
    const float* prenorm_g = (const float*)d_in[2];
    const float* w1        = (const float*)d_in[3];
    const float* b1        = (const float*)d_in[4];
    const float* mult_bias = (const float*)d_in[5];
    const float* w2        = (const float*)d_in[6];
    const float* b2        = (const float*)d_in[7];
    const float* ln_g      = (const float*)d_in[8];
    const float* ln_b      = (const float*)d_in[9];
    float* out = (float*)d_out;

    char* p = (char*)d_ws;
    bf16_t* xgb = (bf16_t*)p; p += (size_t)(NT+1)*DD*2;
    bf16_t* w1t = (bf16_t*)p; p += (size_t)EE*KS1*NW1*32*2;
    bf16_t* w2t = (bf16_t*)p; p += (size_t)EE*KS2*DD*32*2;
    bf16_t* actb = (bf16_t*)p; p += (size_t)EE*KS2*ME*32*2;
    bf16_t* eoA = (bf16_t*)p; p += (size_t)EE*ME*DD*2;
    bf16_t* eoB = (bf16_t*)p; p += (size_t)EE*ME*DD*2;
    int* slot_tok = (int*)p; p += EE*BB*CAP*4;
    int* tok_e0 = (int*)p; p += NT*4;
    int* tok_e1 = (int*)p; p += NT*4;
    int* tok_c0 = (int*)p; p += NT*4;
    int* tok_c1 = (int*)p; p += NT*4;
    float* tok_g0 = (float*)p; p += NT*4;
    float* tok_g1 = (float*)p; p += NT*4;
    float* dpPart = (float*)p; p += EE*NN*4;
    float* z2Part = (float*)p; p += NN*4;
    int* kept0 = (int*)p; p += BB*EE*4;
    unsigned* scanCnt = (unsigned*)p; p += 4;

    k_prep<<<PREP_W2 + 5632, 256, 0, stream>>>(x, prenorm_g, gate_w, w1, w2,
                                               xgb, w1t, w2t,
                                               tok_e0, tok_e1, tok_g0, tok_g1,
                                               tok_c0, tok_c1, dpPart, z2Part, scanCnt);
    k_scan<<<BB*EE, 256, 0, stream>>>(tok_e0, tok_e1, tok_c0, tok_c1, slot_tok, kept0,
                                      dpPart, z2Part, scanCnt, out + (size_t)NT*DD);
    k_ffn1_mfma<<<EE*5*11, 512, 0, stream>>>(xgb, w1t, b1, mult_bias, slot_tok, actb);
    k_ffn2_mfma<<<EE*10*4*2, 256, 0, stream>>>(actb, w2t, eoA, eoB);
    k_combine<<<NT, 128, 0, stream>>>(x, eoA, eoB, tok_e0, tok_e1, tok_c0, tok_c1,
                                      tok_g0, tok_g1, b2, ln_g, ln_b, out);
}